// Round 8
// baseline (976.191 us; speedup 1.0000x reference)
//
#include <hip/hip_runtime.h>
#include <hip/hip_bf16.h>
#include <math.h>

#define NN  16384      // nodes
#define NE  262144     // edges
#define NG  64         // graphs
#define CIN 16         // input colors
#define DD  256        // embedding
#define NHD 8          // heads
#define DHD 32         // head dim
#define DFF 1024       // ffn dim
#define NLY 4          // layers
#define LM  320        // L_max
#define NR  (LM*NG)    // padded rows = 20480
#define QS  768        // fused QKV col count
#define QKW 512        // Q|K row stride in QKb

typedef __attribute__((ext_vector_type(8))) short bf16x8;
typedef __attribute__((ext_vector_type(4))) float f32x4;

__device__ __forceinline__ unsigned short f2bf(float f) {
    union { __hip_bfloat16 h; unsigned short u; } cv;
    cv.h = __float2bfloat16(f);
    return cv.u;
}
__device__ __forceinline__ float bf2f(unsigned short u) {
    return __uint_as_float((unsigned int)u << 16);
}
// async global->LDS 16B: dest = wave-uniform lds base + lane*16
__device__ __forceinline__ void gl_lds16(const unsigned short* g, unsigned short* l) {
    __builtin_amdgcn_global_load_lds(
        (const __attribute__((address_space(1))) unsigned int*)g,
        (__attribute__((address_space(3))) unsigned int*)l, 16, 0, 0);
}

// ---------------------------------------------------------------- utilities
__global__ void zero_int_kernel(int* __restrict__ p, int n) {
    int i = blockIdx.x * 256 + threadIdx.x;
    if (i < n) p[i] = 0;
}
__global__ void zero_f4_kernel(float4* __restrict__ p, int n4) {
    int i = blockIdx.x * 256 + threadIdx.x;
    if (i < n4) p[i] = make_float4(0.f, 0.f, 0.f, 0.f);
}

// ---------------------------------------------------------------- weight prep v2 (LDS-tiled transpose)
// in [L][K][N] f32 -> out [L][N][K] bf16. Tile 64x64. grid (N/64, K/64, L).
__global__ __launch_bounds__(256) void prep_t2_kernel(
    const float* __restrict__ in, unsigned short* __restrict__ out, int K, int N)
{
    __shared__ float Ls[64][68];
    const int n0 = blockIdx.x * 64, k0 = blockIdx.y * 64, l = blockIdx.z;
    const int t = threadIdx.x;
    #pragma unroll
    for (int it = 0; it < 4; ++it) {
        int lin = it * 256 + t;
        int kr = lin >> 4, nc = (lin & 15) * 4;
        float4 v = *(const float4*)&in[((size_t)l * K + k0 + kr) * N + n0 + nc];
        Ls[kr][nc] = v.x; Ls[kr][nc+1] = v.y; Ls[kr][nc+2] = v.z; Ls[kr][nc+3] = v.w;
    }
    __syncthreads();
    #pragma unroll
    for (int it = 0; it < 2; ++it) {
        int lin = it * 256 + t;
        int nr = lin >> 3, kc = (lin & 7) * 8;
        unsigned short pk[8];
        #pragma unroll
        for (int j = 0; j < 8; ++j) pk[j] = f2bf(Ls[kc + j][nr]);
        *(uint4*)&out[((size_t)l * N + n0 + nr) * K + k0 + kc] = *(uint4*)pk;
    }
}

// QKV fused variant: out [l][n(768)][k(256)], softmax scale folded into Q block.
// grid (12, 4, NLY).
__global__ __launch_bounds__(256) void prep_qkv2_kernel(
    const float* __restrict__ Wq, const float* __restrict__ Wk,
    const float* __restrict__ Wv, unsigned short* __restrict__ out)
{
    __shared__ float Ls[64][68];
    const int n0 = blockIdx.x * 64, k0 = blockIdx.y * 64, l = blockIdx.z;
    const float* W = (n0 < 256) ? Wq : (n0 < 512 ? Wk : Wv);
    const int nb = n0 & 255;
    const float sc = (n0 < 256) ? 0.17677669529663687f : 1.f;
    const int t = threadIdx.x;
    #pragma unroll
    for (int it = 0; it < 4; ++it) {
        int lin = it * 256 + t;
        int kr = lin >> 4, nc = (lin & 15) * 4;
        float4 v = *(const float4*)&W[((size_t)l * DD + k0 + kr) * DD + nb + nc];
        Ls[kr][nc] = v.x * sc; Ls[kr][nc+1] = v.y * sc;
        Ls[kr][nc+2] = v.z * sc; Ls[kr][nc+3] = v.w * sc;
    }
    __syncthreads();
    #pragma unroll
    for (int it = 0; it < 2; ++it) {
        int lin = it * 256 + t;
        int nr = lin >> 3, kc = (lin & 7) * 8;
        unsigned short pk[8];
        #pragma unroll
        for (int j = 0; j < 8; ++j) pk[j] = f2bf(Ls[kc + j][nr]);
        *(uint4*)&out[((size_t)l * QS + n0 + nr) * DD + k0 + kc] = *(uint4*)pk;
    }
}

__global__ void prep_bias_kernel(const float* __restrict__ bq, const float* __restrict__ bk,
                                 const float* __restrict__ bv, float* __restrict__ out) {
    int i = blockIdx.x * 256 + threadIdx.x;   // [l][n(768)]
    if (i >= NLY * QS) return;
    int n = i % QS, l = i / QS;
    const float* b = (n < 256) ? bq : (n < 512 ? bk : bv);
    float v = b[l * DD + (n & 255)];
    if (n < 256) v *= 0.17677669529663687f;
    out[i] = v;
}

// ---------------------------------------------------------------- CSR build
__global__ void count_edges_kernel(const int* __restrict__ dst, int* __restrict__ counts) {
    int e = blockIdx.x * 256 + threadIdx.x;
    if (e < NE) atomicAdd(&counts[dst[e]], 1);
}

__global__ __launch_bounds__(256) void scan_kernel(const int* __restrict__ counts,
                                                   int* __restrict__ offsets,
                                                   int* __restrict__ cursor) {
    __shared__ int part[256];
    int t = threadIdx.x;
    int base = t * 64;
    int s = 0;
    for (int i = 0; i < 64; ++i) s += counts[base + i];
    part[t] = s;
    __syncthreads();
    for (int off = 1; off < 256; off <<= 1) {
        int val = (t >= off) ? part[t - off] : 0;
        __syncthreads();
        part[t] += val;
        __syncthreads();
    }
    int run = (t == 0) ? 0 : part[t - 1];
    for (int i = 0; i < 64; ++i) {
        offsets[base + i] = run;
        cursor[base + i]  = run;
        run += counts[base + i];
    }
    if (t == 255) offsets[NN] = run;
}

__global__ void fill_csr_kernel(const int* __restrict__ src, const int* __restrict__ dst,
                                int* __restrict__ cursor, int* __restrict__ csr) {
    int e = blockIdx.x * 256 + threadIdx.x;
    if (e < NE) {
        int p = atomicAdd(&cursor[dst[e]], 1);
        csr[p] = src[e];
    }
}

// ---------------------------------------------------------------- mean aggregation
__global__ __launch_bounds__(256) void agg_mean16_kernel(
    const float* __restrict__ h, const int* __restrict__ offsets,
    const int* __restrict__ csr, float* __restrict__ out)
{
    int node = blockIdx.x * 16 + (threadIdx.x >> 4);
    int d = threadIdx.x & 15;
    int beg = offsets[node], end = offsets[node + 1];
    float acc = 0.f;
    for (int e = beg; e < end; ++e) acc += h[(size_t)csr[e] * CIN + d];
    int dg = end - beg; if (dg < 1) dg = 1;
    out[(size_t)node * CIN + d] = acc * (1.f / (float)dg);
}

__global__ __launch_bounds__(256) void agg_mean_b_kernel(
    const unsigned short* __restrict__ h, const int* __restrict__ offsets,
    const int* __restrict__ csr, unsigned short* __restrict__ out)
{
    int node = blockIdx.x * 4 + (threadIdx.x >> 6);
    int lane = threadIdx.x & 63;
    int beg = offsets[node], end = offsets[node + 1];
    float a0 = 0.f, a1 = 0.f, a2 = 0.f, a3 = 0.f;
    for (int e = beg; e < end; ++e) {
        const ushort4 hv = *(const ushort4*)(h + (size_t)csr[e] * DD + lane * 4);
        a0 += bf2f(hv.x); a1 += bf2f(hv.y); a2 += bf2f(hv.z); a3 += bf2f(hv.w);
    }
    int dg = end - beg; if (dg < 1) dg = 1;
    float inv = 1.f / (float)dg;
    ushort4 ov;
    ov.x = f2bf(a0 * inv); ov.y = f2bf(a1 * inv);
    ov.z = f2bf(a2 * inv); ov.w = f2bf(a3 * inv);
    *(ushort4*)(out + (size_t)node * DD + lane * 4) = ov;
}

// ---------------------------------------------------------------- f32 tiled GEMM (SAGE layer0, K=16) -> bf16 out
template <int ACT, bool DUAL>
__global__ __launch_bounds__(256) void gemm_f32b_kernel(
    const float* __restrict__ A, const float* __restrict__ W,
    const float* __restrict__ A2, const float* __restrict__ W2,
    const float* __restrict__ bias, unsigned short* __restrict__ Cb,
    int M, int N, int K)
{
    __shared__ __align__(16) float As[16][64];
    __shared__ __align__(16) float Ws[16][64];
    const int t  = threadIdx.x;
    const int tx = t & 15, ty = t >> 4;
    const int m0 = blockIdx.y * 64, n0 = blockIdx.x * 64;
    const int arow = t >> 2, acol = (t & 3) * 4;
    const int wrow = t >> 4, wcol = (t & 15) * 4;
    float acc[4][4] = {};
    const int npass = DUAL ? 2 : 1;
    for (int pass = 0; pass < npass; ++pass) {
        const float* Ap = (DUAL && pass) ? A2 : A;
        const float* Wp = (DUAL && pass) ? W2 : W;
        for (int k0 = 0; k0 < K; k0 += 16) {
            __syncthreads();
            float4 av = *(const float4*)(Ap + (size_t)(m0 + arow) * K + k0 + acol);
            As[acol + 0][arow] = av.x;
            As[acol + 1][arow] = av.y;
            As[acol + 2][arow] = av.z;
            As[acol + 3][arow] = av.w;
            *(float4*)&Ws[wrow][wcol] = *(const float4*)(Wp + (size_t)(k0 + wrow) * N + n0 + wcol);
            __syncthreads();
            #pragma unroll
            for (int kk = 0; kk < 16; ++kk) {
                float4 a4 = *(const float4*)&As[kk][ty * 4];
                float4 b4 = *(const float4*)&Ws[kk][tx * 4];
                float aa[4] = {a4.x, a4.y, a4.z, a4.w};
                float bb[4] = {b4.x, b4.y, b4.z, b4.w};
                #pragma unroll
                for (int i = 0; i < 4; ++i)
                    #pragma unroll
                    for (int j = 0; j < 4; ++j)
                        acc[i][j] += aa[i] * bb[j];
            }
        }
    }
    float4 bv = *(const float4*)(bias + n0 + tx * 4);
    float bb4[4] = {bv.x, bv.y, bv.z, bv.w};
    #pragma unroll
    for (int i = 0; i < 4; ++i) {
        float c[4];
        #pragma unroll
        for (int j = 0; j < 4; ++j) {
            c[j] = acc[i][j] + bb4[j];
            if (ACT == 1) c[j] = fmaxf(c[j], 0.f);
        }
        ushort4 ov;
        ov.x = f2bf(c[0]); ov.y = f2bf(c[1]); ov.z = f2bf(c[2]); ov.w = f2bf(c[3]);
        *(ushort4*)(Cb + (size_t)(m0 + ty * 4 + i) * N + n0 + tx * 4) = ov;
    }
}

// ---------------------------------------------------------------- bf16 MFMA GEMM (m97 recipe) — SAGE layers
template <int ACT, bool DUAL, bool OUTF32, bool OUTBF16>
__global__ __launch_bounds__(256) void mfma_gemm_kernel(
    const unsigned short* __restrict__ A,  const unsigned short* __restrict__ Wt,
    const unsigned short* __restrict__ A2, const unsigned short* __restrict__ Wt2,
    const float* __restrict__ bias, float* __restrict__ Cf,
    unsigned short* __restrict__ Cb, int M, int N, int K)
{
    __shared__ __align__(16) unsigned short As[128 * 32];
    __shared__ __align__(16) unsigned short Bs[128 * 32];
    const int t = threadIdx.x;
    const int wave = t >> 6, lane = t & 63;
    const int quad = lane >> 4, r16 = lane & 15;
    const int wr = (wave >> 1) * 64, wc = (wave & 1) * 64;
    const int m0 = blockIdx.y * 128, n0 = blockIdx.x * 128;
    const int srow = t >> 2, sq = (t & 3) * 8;

    unsigned short* la = As + wave * 512;
    unsigned short* lb = Bs + wave * 512;

    f32x4 acc[4][4];
    #pragma unroll
    for (int i = 0; i < 4; ++i)
        #pragma unroll
        for (int j = 0; j < 4; ++j)
            acc[i][j] = (f32x4){0.f, 0.f, 0.f, 0.f};

    const int npass = DUAL ? 2 : 1;
    for (int pass = 0; pass < npass; ++pass) {
        const unsigned short* Ap = (DUAL && pass) ? A2 : A;
        const unsigned short* Wp = (DUAL && pass) ? Wt2 : Wt;
        for (int k0 = 0; k0 < K; k0 += 32) {
            __syncthreads();
            gl_lds16(&Ap[(size_t)(m0 + srow) * K + k0 + sq],       la);
            gl_lds16(&Ap[(size_t)(m0 + 64 + srow) * K + k0 + sq],  la + 2048);
            gl_lds16(&Wp[(size_t)(n0 + srow) * K + k0 + sq],       lb);
            gl_lds16(&Wp[(size_t)(n0 + 64 + srow) * K + k0 + sq],  lb + 2048);
            __syncthreads();
            bf16x8 af[4], bfr[4];
            #pragma unroll
            for (int i = 0; i < 4; ++i)
                af[i] = *(const bf16x8*)&As[(wr + i * 16 + r16) * 32 + quad * 8];
            #pragma unroll
            for (int j = 0; j < 4; ++j)
                bfr[j] = *(const bf16x8*)&Bs[(wc + j * 16 + r16) * 32 + quad * 8];
            #pragma unroll
            for (int i = 0; i < 4; ++i)
                #pragma unroll
                for (int j = 0; j < 4; ++j)
                    acc[i][j] = __builtin_amdgcn_mfma_f32_16x16x32_bf16(
                        af[i], bfr[j], acc[i][j], 0, 0, 0);
        }
    }

    float bcol[4];
    #pragma unroll
    for (int j = 0; j < 4; ++j) bcol[j] = bias[n0 + wc + j * 16 + r16];
    #pragma unroll
    for (int i = 0; i < 4; ++i) {
        const int rowb = m0 + wr + i * 16 + quad * 4;
        #pragma unroll
        for (int rr = 0; rr < 4; ++rr) {
            const size_t rb = (size_t)(rowb + rr) * N;
            #pragma unroll
            for (int j = 0; j < 4; ++j) {
                float v = acc[i][j][rr] + bcol[j];
                if (ACT == 1) v = fmaxf(v, 0.f);
                const int col = n0 + wc + j * 16 + r16;
                if (OUTF32) Cf[rb + col] = v;
                if (OUTBF16) Cb[rb + col] = f2bf(v);
            }
        }
    }
}

// ---------------------------------------------------------------- QKV GEMM: Q,K row-major -> QKb[NR][512];
// V blocks (n0>=512) store V^T directly: Vt[g][dim][key].
__global__ __launch_bounds__(256) void gemm_qkv_kernel(
    const unsigned short* __restrict__ A, const unsigned short* __restrict__ Wt,
    const float* __restrict__ bias, unsigned short* __restrict__ QKb,
    unsigned short* __restrict__ Vt, int K)
{
    __shared__ __align__(16) unsigned short As[128 * 32];
    __shared__ __align__(16) unsigned short Bs[128 * 32];
    const int t = threadIdx.x;
    const int wave = t >> 6, lane = t & 63;
    const int quad = lane >> 4, r16 = lane & 15;
    const int wr = (wave >> 1) * 64, wc = (wave & 1) * 64;
    const int m0 = blockIdx.y * 128, n0 = blockIdx.x * 128;
    const int srow = t >> 2, sq = (t & 3) * 8;
    unsigned short* la = As + wave * 512;
    unsigned short* lb = Bs + wave * 512;

    f32x4 acc[4][4];
    #pragma unroll
    for (int i = 0; i < 4; ++i)
        #pragma unroll
        for (int j = 0; j < 4; ++j)
            acc[i][j] = (f32x4){0.f, 0.f, 0.f, 0.f};

    for (int k0 = 0; k0 < K; k0 += 32) {
        __syncthreads();
        gl_lds16(&A[(size_t)(m0 + srow) * K + k0 + sq],       la);
        gl_lds16(&A[(size_t)(m0 + 64 + srow) * K + k0 + sq],  la + 2048);
        gl_lds16(&Wt[(size_t)(n0 + srow) * K + k0 + sq],      lb);
        gl_lds16(&Wt[(size_t)(n0 + 64 + srow) * K + k0 + sq], lb + 2048);
        __syncthreads();
        bf16x8 af[4], bfr[4];
        #pragma unroll
        for (int i = 0; i < 4; ++i)
            af[i] = *(const bf16x8*)&As[(wr + i * 16 + r16) * 32 + quad * 8];
        #pragma unroll
        for (int j = 0; j < 4; ++j)
            bfr[j] = *(const bf16x8*)&Bs[(wc + j * 16 + r16) * 32 + quad * 8];
        #pragma unroll
        for (int i = 0; i < 4; ++i)
            #pragma unroll
            for (int j = 0; j < 4; ++j)
                acc[i][j] = __builtin_amdgcn_mfma_f32_16x16x32_bf16(
                    af[i], bfr[j], acc[i][j], 0, 0, 0);
    }

    float bcol[4];
    #pragma unroll
    for (int j = 0; j < 4; ++j) bcol[j] = bias[n0 + wc + j * 16 + r16];

    if (n0 < 512) {
        #pragma unroll
        for (int i = 0; i < 4; ++i) {
            const int rowb = m0 + wr + i * 16 + quad * 4;
            #pragma unroll
            for (int rr = 0; rr < 4; ++rr) {
                const size_t rb = (size_t)(rowb + rr) * QKW;
                #pragma unroll
                for (int j = 0; j < 4; ++j)
                    QKb[rb + n0 + wc + j * 16 + r16] = f2bf(acc[i][j][rr] + bcol[j]);
            }
        }
    } else {
        #pragma unroll
        for (int i = 0; i < 4; ++i) {
            const int rowb = m0 + wr + i * 16 + quad * 4;
            const int g = rowb / LM;
            const int key = rowb - g * LM;
            #pragma unroll
            for (int j = 0; j < 4; ++j) {
                const int dim = n0 - 512 + wc + j * 16 + r16;
                unsigned short pk[4];
                #pragma unroll
                for (int rr = 0; rr < 4; ++rr) pk[rr] = f2bf(acc[i][j][rr] + bcol[j]);
                *(uint2*)&Vt[((size_t)g * DD + dim) * LM + key] = *(uint2*)pk;
            }
        }
    }
}

// ---------------------------------------------------------------- GEMM + residual + LayerNorm fused (Wo path)
// 32 rows x 256 cols, 4 waves = 4 col slabs, grid NR/32.
template <bool PERM>
__global__ __launch_bounds__(256) void gemm_ln_kernel(
    const unsigned short* __restrict__ A, const unsigned short* __restrict__ Wt,
    const float* __restrict__ bias, const float* __restrict__ resid,
    const float* __restrict__ gam, const float* __restrict__ bet,
    float* __restrict__ outHf, unsigned short* __restrict__ outHb, int K)
{
    __shared__ __align__(16) unsigned short As[32 * 32];
    __shared__ __align__(16) unsigned short Bs[256 * 32];
    __shared__ float red[2][4][32];
    const int t = threadIdx.x;
    const int wave = t >> 6, lane = t & 63;
    const int quad = lane >> 4, r16 = lane & 15;
    const int wc = wave * 64;
    const int m0 = blockIdx.x * 32;
    const int sr = lane >> 2, sq = (lane & 3) * 8;

    f32x4 acc[2][4];
    #pragma unroll
    for (int i = 0; i < 2; ++i)
        #pragma unroll
        for (int j = 0; j < 4; ++j)
            acc[i][j] = (f32x4){0.f, 0.f, 0.f, 0.f};

    for (int k0 = 0; k0 < K; k0 += 32) {
        __syncthreads();
        if (wave < 2)
            gl_lds16(&A[(size_t)(m0 + wave * 16 + sr) * K + k0 + sq], As + wave * 512);
        #pragma unroll
        for (int c = 0; c < 4; ++c)
            gl_lds16(&Wt[(size_t)(wc + c * 16 + sr) * K + k0 + sq],
                     Bs + wave * 2048 + c * 512);
        __syncthreads();
        bf16x8 af[2], bfr[4];
        #pragma unroll
        for (int i = 0; i < 2; ++i)
            af[i] = *(const bf16x8*)&As[(i * 16 + r16) * 32 + quad * 8];
        #pragma unroll
        for (int j = 0; j < 4; ++j)
            bfr[j] = *(const bf16x8*)&Bs[(wc + j * 16 + r16) * 32 + quad * 8];
        #pragma unroll
        for (int i = 0; i < 2; ++i)
            #pragma unroll
            for (int j = 0; j < 4; ++j)
                acc[i][j] = __builtin_amdgcn_mfma_f32_16x16x32_bf16(
                    af[i], bfr[j], acc[i][j], 0, 0, 0);
    }

    float bcol[4];
    #pragma unroll
    for (int j = 0; j < 4; ++j) bcol[j] = bias[wc + j * 16 + r16];

    #pragma unroll
    for (int i = 0; i < 2; ++i) {
        const int row = i * 16 + quad * 4;
        #pragma unroll
        for (int rr = 0; rr < 4; ++rr) {
            const size_t rb = (size_t)(m0 + row + rr) * DD;
            float s1 = 0.f, s2 = 0.f;
            #pragma unroll
            for (int j = 0; j < 4; ++j) {
                float v = acc[i][j][rr] + bcol[j] + resid[rb + wc + j * 16 + r16];
                acc[i][j][rr] = v;
                s1 += v;
                s2 += v * v;
            }
            #pragma unroll
            for (int off = 1; off < 16; off <<= 1) {
                s1 += __shfl_xor(s1, off, 64);
                s2 += __shfl_xor(s2, off, 64);
            }
            if (r16 == 0) {
                red[0][wave][row + rr] = s1;
                red[1][wave][row + rr] = s2;
            }
        }
    }
    __syncthreads();
    #pragma unroll
    for (int i = 0; i < 2; ++i) {
        const int row = i * 16 + quad * 4;
        #pragma unroll
        for (int rr = 0; rr < 4; ++rr) {
            const int gr = m0 + row + rr;
            float s1 = red[0][0][row + rr] + red[0][1][row + rr]
                     + red[0][2][row + rr] + red[0][3][row + rr];
            float s2 = red[1][0][row + rr] + red[1][1][row + rr]
                     + red[1][2][row + rr] + red[1][3][row + rr];
            float mean = s1 * (1.f / 256.f);
            float var  = s2 * (1.f / 256.f) - mean * mean;
            float rs = rsqrtf(var + 1e-5f);
            size_t fb;
            if (PERM) {
                int gg = gr / LM, pos = gr - gg * LM;
                fb = ((size_t)pos * NG + gg) * DD;
            } else {
                fb = (size_t)gr * DD;
            }
            const size_t hb = (size_t)gr * DD;
            #pragma unroll
            for (int j = 0; j < 4; ++j) {
                const int col = wc + j * 16 + r16;
                float ov = (acc[i][j][rr] - mean) * rs * gam[col] + bet[col];
                outHf[fb + col] = ov;
                outHb[hb + col] = f2bf(ov);
            }
        }
    }
}

// ---------------------------------------------------------------- fused FFN + residual + LayerNorm
// h = LN(resid + relu(H@W1+b1)@W2 + b2). 32 rows/block, 4 waves.
// Stage H (32x256) in LDS once; loop 16 chunks of 64 FFN dims:
//   stage-1: F1^T = W1·H^T via MFMA (wave computes 16 ffn dims), relu -> packed b64 -> F1 LDS
//   stage-2: acc2 += F1 @ W2chunk (W2 B-fragments straight from global, L2-hot)
template <bool PERM>
__global__ __launch_bounds__(256) void ffn_ln_kernel(
    const unsigned short* __restrict__ Hb, const unsigned short* __restrict__ W1t,
    const float* __restrict__ b1, const unsigned short* __restrict__ W2t,
    const float* __restrict__ b2, const float* __restrict__ resid,
    const float* __restrict__ gam, const float* __restrict__ bet,
    float* __restrict__ outHf, unsigned short* __restrict__ outHb)
{
    __shared__ __align__(16) unsigned short As[32 * 264];   // H tile, pad 264 (16.9 KB)
    __shared__ __align__(16) unsigned short F1[32 * 72];    // F1 chunk, pad 72 (4.6 KB)
    __shared__ float red[2][4][32];
    const int t = threadIdx.x;
    const int wave = t >> 6, lane = t & 63;
    const int quad = lane >> 4, r16 = lane & 15;
    const int wc = wave * 64;
    const int m0 = blockIdx.x * 32;

    // stage H rows (coalesced uint4, padded LDS rows)
    #pragma unroll
    for (int it = 0; it < 4; ++it) {
        int lin = it * 256 + t;
        int row = lin >> 5, c8 = (lin & 31) * 8;
        *(uint4*)&As[row * 264 + c8] = *(const uint4*)&Hb[(size_t)(m0 + row) * DD + c8];
    }

    f32x4 acc2[2][4];
    #pragma unroll
    for (int i = 0; i < 2; ++i)
        #pragma unroll
        for (int j = 0; j < 4; ++j)
            acc2[i][j] = (f32x4){0.f, 0.f, 0.f, 0.f};
    __syncthreads();

    for (int ch = 0; ch < 16; ++ch) {
        const int fb = ch * 64;
        // ---- stage-1: wave computes its 16 ffn dims (m = fb + wave*16 + r16)
        f32x4 acc1[2];
        acc1[0] = (f32x4){0.f, 0.f, 0.f, 0.f};
        acc1[1] = (f32x4){0.f, 0.f, 0.f, 0.f};
        #pragma unroll
        for (int ks = 0; ks < 8; ++ks) {
            bf16x8 wf = *(const bf16x8*)&W1t[(size_t)(fb + wave * 16 + r16) * DD
                                             + ks * 32 + quad * 8];
            #pragma unroll
            for (int i = 0; i < 2; ++i) {
                bf16x8 hf = *(const bf16x8*)&As[(i * 16 + r16) * 264 + ks * 32 + quad * 8];
                acc1[i] = __builtin_amdgcn_mfma_f32_16x16x32_bf16(wf, hf, acc1[i], 0, 0, 0);
            }
        }
        // relu + bias, pack 4 consecutive ffn dims -> b64 LDS write
        float b1r[4];
        #pragma unroll
        for (int rr = 0; rr < 4; ++rr) b1r[rr] = b1[fb + wave * 16 + quad * 4 + rr];
        #pragma unroll
        for (int i = 0; i < 2; ++i) {
            unsigned short pk[4];
            #pragma unroll
            for (int rr = 0; rr < 4; ++rr)
                pk[rr] = f2bf(fmaxf(acc1[i][rr] + b1r[rr], 0.f));
            *(uint2*)&F1[(i * 16 + r16) * 72 + wave * 16 + quad * 4] = *(uint2*)pk;
        }
        __syncthreads();
        // ---- stage-2: acc2 += F1 @ W2chunk
        #pragma unroll
        for (int ks = 0; ks < 2; ++ks) {
            bf16x8 af[2];
            #pragma unroll
            for (int i = 0; i < 2; ++i)
                af[i] = *(const bf16x8*)&F1[(i * 16 + r16) * 72 + ks * 32 + quad * 8];
            #pragma unroll
            for (int j = 0; j < 4; ++j) {
                bf16x8 w2 = *(const bf16x8*)&W2t[(size_t)(wc + j * 16 + r16) * DFF
                                                 + fb + ks * 32 + quad * 8];
                #pragma unroll
                for (int i = 0; i < 2; ++i)
                    acc2[i][j] = __builtin_amdgcn_mfma_f32_16x16x32_bf16(
                        af[i], w2, acc2[i][j], 0, 0, 0);
            }
        }
        __syncthreads();
    }

    // ---- epilogue: bias + residual + LN (identical to gemm_ln)
    float bcol[4];
    #pragma unroll
    for (int j = 0; j < 4; ++j) bcol[j] = b2[wc + j * 16 + r16];

    #pragma unroll
    for (int i = 0; i < 2; ++i) {
        const int row = i * 16 + quad * 4;
        #pragma unroll
        for (int rr = 0; rr < 4; ++rr) {
            const size_t rb = (size_t)(m0 + row + rr) * DD;
            float s1 = 0.f, s2 = 0.f;
            #pragma unroll
            for (int j = 0; j < 4; ++j) {
                float v = acc2[i][j][rr] + bcol[j] + resid[rb + wc + j * 16 + r16];
                acc2[i][j][rr] = v;
                s1 += v;
                s2 += v * v;
            }
            #pragma unroll
            for (int off = 1; off < 16; off <<= 1) {
                s1 += __shfl_xor(s1, off, 64);
                s2 += __shfl_xor(s2, off, 64);
            }
            if (r16 == 0) {
                red[0][wave][row + rr] = s1;
                red[1][wave][row + rr] = s2;
            }
        }
    }
    __syncthreads();
    #pragma unroll
    for (int i = 0; i < 2; ++i) {
        const int row = i * 16 + quad * 4;
        #pragma unroll
        for (int rr = 0; rr < 4; ++rr) {
            const int gr = m0 + row + rr;
            float s1 = red[0][0][row + rr] + red[0][1][row + rr]
                     + red[0][2][row + rr] + red[0][3][row + rr];
            float s2 = red[1][0][row + rr] + red[1][1][row + rr]
                     + red[1][2][row + rr] + red[1][3][row + rr];
            float mean = s1 * (1.f / 256.f);
            float var  = s2 * (1.f / 256.f) - mean * mean;
            float rs = rsqrtf(var + 1e-5f);
            size_t fbo;
            if (PERM) {
                int gg = gr / LM, pos = gr - gg * LM;
                fbo = ((size_t)pos * NG + gg) * DD;
            } else {
                fbo = (size_t)gr * DD;
            }
            const size_t hb = (size_t)gr * DD;
            #pragma unroll
            for (int j = 0; j < 4; ++j) {
                const int col = wc + j * 16 + r16;
                float ov = (acc2[i][j][rr] - mean) * rs * gam[col] + bet[col];
                outHf[fbo + col] = ov;
                outHb[hb + col] = f2bf(ov);
            }
        }
    }
}

// ---------------------------------------------------------------- pack to graph-major padded [g][pos][D]
__global__ __launch_bounds__(256) void pack_kernel(
    const float* __restrict__ z, const int* __restrict__ batches,
    float* __restrict__ Hf, unsigned short* __restrict__ Hb)
{
    int node = blockIdx.x * 4 + (threadIdx.x >> 6);
    int lane = threadIdx.x & 63;
    int lo = 0, hi = NG;
    while (lo < hi) {
        int mid = (lo + hi + 1) >> 1;
        if (batches[mid] <= node) lo = mid; else hi = mid - 1;
    }
    int pos = node - batches[lo];
    size_t base = ((size_t)lo * LM + pos) * DD + lane * 4;
    float4 zv = *(const float4*)(z + (size_t)node * DD + lane * 4);
    *(float4*)(Hf + base) = zv;
    ushort4 hb;
    hb.x = f2bf(zv.x); hb.y = f2bf(zv.y); hb.z = f2bf(zv.z); hb.w = f2bf(zv.w);
    *(ushort4*)(Hb + base) = hb;
}

// ---------------------------------------------------------------- MFMA flash attention (no barriers)
__global__ __launch_bounds__(256) void attn_mfma_kernel(
    const unsigned short* __restrict__ qk, const unsigned short* __restrict__ vt,
    const int* __restrict__ batches, unsigned short* __restrict__ o)
{
    __shared__ __align__(16) unsigned short Pa[4][32 * 40];
    const int bx = blockIdx.x;
    const int g = bx & 63;
    const int r = bx >> 6;            // 0..19
    const int q0 = (r >> 1) * 32;
    const int tid = threadIdx.x;
    const int wave = tid >> 6;
    const int h = (r & 1) * 4 + wave;
    const int lane = tid & 63;
    const int quad = lane >> 4, r16 = lane & 15;
    const int len = batches[g + 1] - batches[g];
    const size_t gq = (size_t)g * LM;
    unsigned short* pa = Pa[wave];

    bf16x8 qf[2];
    #pragma unroll
    for (int i = 0; i < 2; ++i)
        qf[i] = *(const bf16x8*)(qk + (gq + q0 + i * 16 + r16) * QKW + h * 32 + quad * 8);
    bf16x8 onesf;
    #pragma unroll
    for (int j = 0; j < 8; ++j) onesf[j] = (short)0x3F80;   // bf16 1.0

    f32x4 oacc[2][2], lacc[2];
    #pragma unroll
    for (int i = 0; i < 2; ++i) {
        lacc[i] = (f32x4){0.f, 0.f, 0.f, 0.f};
        #pragma unroll
        for (int nt = 0; nt < 2; ++nt)
            oacc[i][nt] = (f32x4){0.f, 0.f, 0.f, 0.f};
    }

    for (int t0 = 0; t0 < len; t0 += 32) {
        bf16x8 kf[2], vf[2];
        #pragma unroll
        for (int mt = 0; mt < 2; ++mt) {
            int kr = t0 + mt * 16 + r16; if (kr > LM - 1) kr = LM - 1;
            kf[mt] = *(const bf16x8*)(qk + (gq + kr) * QKW + 256 + h * 32 + quad * 8);
        }
        #pragma unroll
        for (int nt = 0; nt < 2; ++nt)
            vf[nt] = *(const bf16x8*)(vt + ((size_t)g * DD + h * 32 + nt * 16 + r16) * LM
                                      + t0 + quad * 8);
        f32x4 st[2][2];
        #pragma unroll
        for (int mt = 0; mt < 2; ++mt)
            #pragma unroll
            for (int i = 0; i < 2; ++i)
                st[mt][i] = (f32x4){0.f, 0.f, 0.f, 0.f};
        #pragma unroll
        for (int mt = 0; mt < 2; ++mt)
            #pragma unroll
            for (int i = 0; i < 2; ++i)
                st[mt][i] = __builtin_amdgcn_mfma_f32_16x16x32_bf16(
                    kf[mt], qf[i], st[mt][i], 0, 0, 0);
        #pragma unroll
        for (int i = 0; i < 2; ++i) {
            #pragma unroll
            for (int mt = 0; mt < 2; ++mt) {
                float pr[4];
                #pragma unroll
                for (int rr = 0; rr < 4; ++rr) {
                    int key = t0 + mt * 16 + quad * 4 + rr;
                    pr[rr] = (key < len) ? __expf(st[mt][i][rr]) : 0.f;
                }
                uint2 w;
                w.x = ((unsigned)f2bf(pr[1]) << 16) | f2bf(pr[0]);
                w.y = ((unsigned)f2bf(pr[3]) << 16) | f2bf(pr[2]);
                *(uint2*)&pa[(i * 16 + r16) * 40 + mt * 16 + quad * 4] = w;
            }
        }
        __asm__ volatile("s_waitcnt lgkmcnt(0)" ::: "memory");
        bf16x8 pf[2];
        #pragma unroll
        for (int i = 0; i < 2; ++i)
            pf[i] = *(const bf16x8*)&pa[(i * 16 + r16) * 40 + quad * 8];
        #pragma unroll
        for (int i = 0; i < 2; ++i) {
            #pragma unroll
            for (int nt = 0; nt < 2; ++nt)
                oacc[i][nt] = __builtin_amdgcn_mfma_f32_16x16x32_bf16(
                    pf[i], vf[nt], oacc[i][nt], 0, 0, 0);
            lacc[i] = __builtin_amdgcn_mfma_f32_16x16x32_bf16(
                pf[i], onesf, lacc[i], 0, 0, 0);
        }
    }
    #pragma unroll
    for (int i = 0; i < 2; ++i) {
        #pragma unroll
        for (int rr = 0; rr < 4; ++rr) {
            float inv = 1.f / lacc[i][rr];
            size_t base = (gq + q0 + i * 16 + quad * 4 + rr) * DD + h * 32;
            #pragma unroll
            for (int nt = 0; nt < 2; ++nt)
                o[base + nt * 16 + r16] = f2bf(oacc[i][nt][rr] * inv);
        }
    }
}

// ---------------------------------------------------------------- launcher
extern "C" void kernel_launch(void* const* d_in, const int* in_sizes, int n_in,
                              void* d_out, int out_size, void* d_ws, size_t ws_size,
                              hipStream_t stream) {
    const float* x       = (const float*)d_in[0];
    const int*   ei      = (const int*)d_in[1];
    const int*   batches = (const int*)d_in[2];
    const float* sW0  = (const float*)d_in[4];
    const float* sWn0 = (const float*)d_in[5];
    const float* sb0  = (const float*)d_in[6];
    const float* sW1  = (const float*)d_in[7];
    const float* sWn1 = (const float*)d_in[8];
    const float* sb1  = (const float*)d_in[9];
    const float* sW2  = (const float*)d_in[10];
    const float* sWn2 = (const float*)d_in[11];
    const float* sb2  = (const float*)d_in[12];
    const float* Wq   = (const float*)d_in[13];
    const float* Wk   = (const float*)d_in[14];
    const float* Wv   = (const float*)d_in[15];
    const float* bq   = (const float*)d_in[16];
    const float* bk   = (const float*)d_in[17];
    const float* bv   = (const float*)d_in[18];
    const float* Wo   = (const float*)d_in[19];
    const float* bo   = (const float*)d_in[20];
    const float* ln1g = (const float*)d_in[21];
    const float* ln1b = (const float*)d_in[22];
    const float* ln2g = (const float*)d_in[23];
    const float* ln2b = (const float*)d_in[24];
    const float* W1   = (const float*)d_in[25];
    const float* b1   = (const float*)d_in[26];
    const float* W2   = (const float*)d_in[27];
    const float* b2   = (const float*)d_in[28];

    char* p = (char*)d_ws;
    auto alloc = [&](size_t bytes) {
        char* r = p;
        p += (bytes + 255) & ~(size_t)255;
        return r;
    };
    int*   counts  = (int*)alloc((size_t)NN * 4);
    int*   offsets = (int*)alloc((size_t)(NN + 1) * 4);
    int*   cursor  = (int*)alloc((size_t)NN * 4);
    int*   csr     = (int*)alloc((size_t)NE * 4);
    float* agg0    = (float*)alloc((size_t)NN * CIN * 4);
    unsigned short* z0b = (unsigned short*)alloc((size_t)NN * DD * 2);
    unsigned short* a1b = (unsigned short*)alloc((size_t)NN * DD * 2);
    unsigned short* z1b = (unsigned short*)alloc((size_t)NN * DD * 2);
    unsigned short* a2b = (unsigned short*)alloc((size_t)NN * DD * 2);
    float* z2f     = (float*)alloc((size_t)NN * DD * 4);   // dead after pack -> Vt aliases it
    unsigned short* Vt = (unsigned short*)z2f;             // [64][256][320] bf16 = 10.5 MB
    float* Hf      = (float*)alloc((size_t)NR * DD * 4);
    unsigned short* Hb = (unsigned short*)alloc((size_t)NR * DD * 2);
    unsigned short* Ob = (unsigned short*)alloc((size_t)NR * DD * 2);
    unsigned short* QKb = (unsigned short*)alloc((size_t)NR * QKW * 2);  // 21 MB
    unsigned short* Wqkvt = (unsigned short*)alloc((size_t)NLY * QS * DD * 2);
    unsigned short* Wot   = (unsigned short*)alloc((size_t)NLY * DD * DD * 2);
    unsigned short* W1t   = (unsigned short*)alloc((size_t)NLY * DFF * DD * 2);
    unsigned short* W2t   = (unsigned short*)alloc((size_t)NLY * DD * DFF * 2);
    unsigned short* sW1t  = (unsigned short*)alloc((size_t)DD * DD * 2);
    unsigned short* sWn1t = (unsigned short*)alloc((size_t)DD * DD * 2);
    unsigned short* sW2t  = (unsigned short*)alloc((size_t)DD * DD * 2);
    unsigned short* sWn2t = (unsigned short*)alloc((size_t)DD * DD * 2);
    float* bqkvp   = (float*)alloc((size_t)NLY * QS * 4);

    // ---- weight prep (tiled transpose) ----
    prep_qkv2_kernel<<<dim3(QS / 64, DD / 64, NLY), 256, 0, stream>>>(Wq, Wk, Wv, Wqkvt);
    prep_t2_kernel<<<dim3(DD / 64, DD / 64, NLY), 256, 0, stream>>>(Wo, Wot, DD, DD);
    prep_t2_kernel<<<dim3(DFF / 64, DD / 64, NLY), 256, 0, stream>>>(W1, W1t, DD, DFF);
    prep_t2_kernel<<<dim3(DD / 64, DFF / 64, NLY), 256, 0, stream>>>(W2, W2t, DFF, DD);
    prep_t2_kernel<<<dim3(DD / 64, DD / 64, 1), 256, 0, stream>>>(sW1, sW1t, DD, DD);
    prep_t2_kernel<<<dim3(DD / 64, DD / 64, 1), 256, 0, stream>>>(sWn1, sWn1t, DD, DD);
    prep_t2_kernel<<<dim3(DD / 64, DD / 64, 1), 256, 0, stream>>>(sW2, sW2t, DD, DD);
    prep_t2_kernel<<<dim3(DD / 64, DD / 64, 1), 256, 0, stream>>>(sWn2, sWn2t, DD, DD);
    prep_bias_kernel<<<(NLY * QS + 255) / 256, 256, 0, stream>>>(bq, bk, bv, bqkvp);

    // ---- CSR build ----
    zero_int_kernel<<<NN / 256, 256, 0, stream>>>(counts, NN);
    count_edges_kernel<<<NE / 256, 256, 0, stream>>>(ei + NE, counts);
    scan_kernel<<<1, 256, 0, stream>>>(counts, offsets, cursor);
    fill_csr_kernel<<<NE / 256, 256, 0, stream>>>(ei, ei + NE, cursor, csr);

    // ---- SAGE ----
    agg_mean16_kernel<<<NN / 16, 256, 0, stream>>>(x, offsets, csr, agg0);
    gemm_f32b_kernel<1, true><<<dim3(DD / 64, NN / 64), 256, 0, stream>>>(
        x, sW0, agg0, sWn0, sb0, z0b, NN, DD, CIN);
    agg_mean_b_kernel<<<NN / 4, 256, 0, stream>>>(z0b, offsets, csr, a1b);
    mfma_gemm_kernel<1, true, false, true><<<dim3(DD / 128, NN / 128), 256, 0, stream>>>(
        z0b, sW1t, a1b, sWn1t, sb1, nullptr, z1b, NN, DD, DD);
    agg_mean_b_kernel<<<NN / 4, 256, 0, stream>>>(z1b, offsets, csr, a2b);
    mfma_gemm_kernel<0, true, true, false><<<dim3(DD / 128, NN / 128), 256, 0, stream>>>(
        z1b, sW2t, a2b, sWn2t, sb2, z2f, nullptr, NN, DD, DD);

    // ---- pack (graph-major) ----
    zero_f4_kernel<<<((size_t)NR * DD / 4) / 256, 256, 0, stream>>>((float4*)Hf, NR * DD / 4);
    zero_f4_kernel<<<((size_t)NR * DD / 8) / 256, 256, 0, stream>>>((float4*)Hb, NR * DD / 8);
    pack_kernel<<<NN / 4, 256, 0, stream>>>(z2f, batches, Hf, Hb);

    // ---- transformer ----
    for (int l = 0; l < NLY; ++l) {
        gemm_qkv_kernel<<<dim3(QS / 128, NR / 128), 256, 0, stream>>>(
            Hb, Wqkvt + (size_t)l * QS * DD, bqkvp + (size_t)l * QS, QKb, Vt, DD);
        attn_mfma_kernel<<<NG * 20, 256, 0, stream>>>(QKb, Vt, batches, Ob);
        gemm_ln_kernel<false><<<NR / 32, 256, 0, stream>>>(
            Ob, Wot + (size_t)l * DD * DD, bo + (size_t)l * DD, Hf,
            ln1g + (size_t)l * DD, ln1b + (size_t)l * DD, Hf, Hb, DD);
        if (l == NLY - 1)
            ffn_ln_kernel<true><<<NR / 32, 256, 0, stream>>>(
                Hb, W1t + (size_t)l * DFF * DD, b1 + (size_t)l * DFF,
                W2t + (size_t)l * DD * DFF, b2 + (size_t)l * DD, Hf,
                ln2g + (size_t)l * DD, ln2b + (size_t)l * DD, (float*)d_out, Hb);
        else
            ffn_ln_kernel<false><<<NR / 32, 256, 0, stream>>>(
                Hb, W1t + (size_t)l * DFF * DD, b1 + (size_t)l * DFF,
                W2t + (size_t)l * DD * DFF, b2 + (size_t)l * DD, Hf,
                ln2g + (size_t)l * DD, ln2b + (size_t)l * DD, Hf, Hb);
    }
}

// Round 9
// 847.042 us; speedup vs baseline: 1.1525x; 1.1525x over previous
//
#include <hip/hip_runtime.h>
#include <hip/hip_bf16.h>
#include <math.h>

#define NN  16384      // nodes
#define NE  262144     // edges
#define NG  64         // graphs
#define CIN 16         // input colors
#define DD  256        // embedding
#define NHD 8          // heads
#define DHD 32         // head dim
#define DFF 1024       // ffn dim
#define NLY 4          // layers
#define LM  320        // L_max
#define NR  (LM*NG)    // padded rows = 20480
#define QS  768        // fused QKV col count
#define QKW 512        // Q|K row stride in QKb

typedef __attribute__((ext_vector_type(8))) short bf16x8;
typedef __attribute__((ext_vector_type(4))) float f32x4;

__device__ __forceinline__ unsigned short f2bf(float f) {
    union { __hip_bfloat16 h; unsigned short u; } cv;
    cv.h = __float2bfloat16(f);
    return cv.u;
}
__device__ __forceinline__ float bf2f(unsigned short u) {
    return __uint_as_float((unsigned int)u << 16);
}
// async global->LDS 16B: dest = wave-uniform lds base + lane*16
__device__ __forceinline__ void gl_lds16(const unsigned short* g, unsigned short* l) {
    __builtin_amdgcn_global_load_lds(
        (const __attribute__((address_space(1))) unsigned int*)g,
        (__attribute__((address_space(3))) unsigned int*)l, 16, 0, 0);
}

// ---------------------------------------------------------------- utilities
__global__ void zero_int_kernel(int* __restrict__ p, int n) {
    int i = blockIdx.x * 256 + threadIdx.x;
    if (i < n) p[i] = 0;
}
__global__ void zero_f4_kernel(float4* __restrict__ p, int n4) {
    int i = blockIdx.x * 256 + threadIdx.x;
    if (i < n4) p[i] = make_float4(0.f, 0.f, 0.f, 0.f);
}

// ---------------------------------------------------------------- weight prep v2 (LDS-tiled transpose)
// in [L][K][N] f32 -> out [L][N][K] bf16. Tile 64x64. grid (N/64, K/64, L).
__global__ __launch_bounds__(256) void prep_t2_kernel(
    const float* __restrict__ in, unsigned short* __restrict__ out, int K, int N)
{
    __shared__ float Ls[64][68];
    const int n0 = blockIdx.x * 64, k0 = blockIdx.y * 64, l = blockIdx.z;
    const int t = threadIdx.x;
    #pragma unroll
    for (int it = 0; it < 4; ++it) {
        int lin = it * 256 + t;
        int kr = lin >> 4, nc = (lin & 15) * 4;
        float4 v = *(const float4*)&in[((size_t)l * K + k0 + kr) * N + n0 + nc];
        Ls[kr][nc] = v.x; Ls[kr][nc+1] = v.y; Ls[kr][nc+2] = v.z; Ls[kr][nc+3] = v.w;
    }
    __syncthreads();
    #pragma unroll
    for (int it = 0; it < 2; ++it) {
        int lin = it * 256 + t;
        int nr = lin >> 3, kc = (lin & 7) * 8;
        unsigned short pk[8];
        #pragma unroll
        for (int j = 0; j < 8; ++j) pk[j] = f2bf(Ls[kc + j][nr]);
        *(uint4*)&out[((size_t)l * N + n0 + nr) * K + k0 + kc] = *(uint4*)pk;
    }
}

// QKV fused variant: out [l][n(768)][k(256)], softmax scale folded into Q block.
__global__ __launch_bounds__(256) void prep_qkv2_kernel(
    const float* __restrict__ Wq, const float* __restrict__ Wk,
    const float* __restrict__ Wv, unsigned short* __restrict__ out)
{
    __shared__ float Ls[64][68];
    const int n0 = blockIdx.x * 64, k0 = blockIdx.y * 64, l = blockIdx.z;
    const float* W = (n0 < 256) ? Wq : (n0 < 512 ? Wk : Wv);
    const int nb = n0 & 255;
    const float sc = (n0 < 256) ? 0.17677669529663687f : 1.f;
    const int t = threadIdx.x;
    #pragma unroll
    for (int it = 0; it < 4; ++it) {
        int lin = it * 256 + t;
        int kr = lin >> 4, nc = (lin & 15) * 4;
        float4 v = *(const float4*)&W[((size_t)l * DD + k0 + kr) * DD + nb + nc];
        Ls[kr][nc] = v.x * sc; Ls[kr][nc+1] = v.y * sc;
        Ls[kr][nc+2] = v.z * sc; Ls[kr][nc+3] = v.w * sc;
    }
    __syncthreads();
    #pragma unroll
    for (int it = 0; it < 2; ++it) {
        int lin = it * 256 + t;
        int nr = lin >> 3, kc = (lin & 7) * 8;
        unsigned short pk[8];
        #pragma unroll
        for (int j = 0; j < 8; ++j) pk[j] = f2bf(Ls[kc + j][nr]);
        *(uint4*)&out[((size_t)l * QS + n0 + nr) * DD + k0 + kc] = *(uint4*)pk;
    }
}

__global__ void prep_bias_kernel(const float* __restrict__ bq, const float* __restrict__ bk,
                                 const float* __restrict__ bv, float* __restrict__ out) {
    int i = blockIdx.x * 256 + threadIdx.x;   // [l][n(768)]
    if (i >= NLY * QS) return;
    int n = i % QS, l = i / QS;
    const float* b = (n < 256) ? bq : (n < 512 ? bk : bv);
    float v = b[l * DD + (n & 255)];
    if (n < 256) v *= 0.17677669529663687f;
    out[i] = v;
}

// ---------------------------------------------------------------- CSR build
__global__ void count_edges_kernel(const int* __restrict__ dst, int* __restrict__ counts) {
    int e = blockIdx.x * 256 + threadIdx.x;
    if (e < NE) atomicAdd(&counts[dst[e]], 1);
}

__global__ __launch_bounds__(256) void scan_kernel(const int* __restrict__ counts,
                                                   int* __restrict__ offsets,
                                                   int* __restrict__ cursor) {
    __shared__ int part[256];
    int t = threadIdx.x;
    int base = t * 64;
    int s = 0;
    for (int i = 0; i < 64; ++i) s += counts[base + i];
    part[t] = s;
    __syncthreads();
    for (int off = 1; off < 256; off <<= 1) {
        int val = (t >= off) ? part[t - off] : 0;
        __syncthreads();
        part[t] += val;
        __syncthreads();
    }
    int run = (t == 0) ? 0 : part[t - 1];
    for (int i = 0; i < 64; ++i) {
        offsets[base + i] = run;
        cursor[base + i]  = run;
        run += counts[base + i];
    }
    if (t == 255) offsets[NN] = run;
}

__global__ void fill_csr_kernel(const int* __restrict__ src, const int* __restrict__ dst,
                                int* __restrict__ cursor, int* __restrict__ csr) {
    int e = blockIdx.x * 256 + threadIdx.x;
    if (e < NE) {
        int p = atomicAdd(&cursor[dst[e]], 1);
        csr[p] = src[e];
    }
}

// ---------------------------------------------------------------- mean aggregation
__global__ __launch_bounds__(256) void agg_mean16_kernel(
    const float* __restrict__ h, const int* __restrict__ offsets,
    const int* __restrict__ csr, float* __restrict__ out)
{
    int node = blockIdx.x * 16 + (threadIdx.x >> 4);
    int d = threadIdx.x & 15;
    int beg = offsets[node], end = offsets[node + 1];
    float acc = 0.f;
    for (int e = beg; e < end; ++e) acc += h[(size_t)csr[e] * CIN + d];
    int dg = end - beg; if (dg < 1) dg = 1;
    out[(size_t)node * CIN + d] = acc * (1.f / (float)dg);
}

__global__ __launch_bounds__(256) void agg_mean_b_kernel(
    const unsigned short* __restrict__ h, const int* __restrict__ offsets,
    const int* __restrict__ csr, unsigned short* __restrict__ out)
{
    int node = blockIdx.x * 4 + (threadIdx.x >> 6);
    int lane = threadIdx.x & 63;
    int beg = offsets[node], end = offsets[node + 1];
    float a0 = 0.f, a1 = 0.f, a2 = 0.f, a3 = 0.f;
    for (int e = beg; e < end; ++e) {
        const ushort4 hv = *(const ushort4*)(h + (size_t)csr[e] * DD + lane * 4);
        a0 += bf2f(hv.x); a1 += bf2f(hv.y); a2 += bf2f(hv.z); a3 += bf2f(hv.w);
    }
    int dg = end - beg; if (dg < 1) dg = 1;
    float inv = 1.f / (float)dg;
    ushort4 ov;
    ov.x = f2bf(a0 * inv); ov.y = f2bf(a1 * inv);
    ov.z = f2bf(a2 * inv); ov.w = f2bf(a3 * inv);
    *(ushort4*)(out + (size_t)node * DD + lane * 4) = ov;
}

// ---------------------------------------------------------------- f32 tiled GEMM (SAGE layer0, K=16) -> bf16 out
template <int ACT, bool DUAL>
__global__ __launch_bounds__(256) void gemm_f32b_kernel(
    const float* __restrict__ A, const float* __restrict__ W,
    const float* __restrict__ A2, const float* __restrict__ W2,
    const float* __restrict__ bias, unsigned short* __restrict__ Cb,
    int M, int N, int K)
{
    __shared__ __align__(16) float As[16][64];
    __shared__ __align__(16) float Ws[16][64];
    const int t  = threadIdx.x;
    const int tx = t & 15, ty = t >> 4;
    const int m0 = blockIdx.y * 64, n0 = blockIdx.x * 64;
    const int arow = t >> 2, acol = (t & 3) * 4;
    const int wrow = t >> 4, wcol = (t & 15) * 4;
    float acc[4][4] = {};
    const int npass = DUAL ? 2 : 1;
    for (int pass = 0; pass < npass; ++pass) {
        const float* Ap = (DUAL && pass) ? A2 : A;
        const float* Wp = (DUAL && pass) ? W2 : W;
        for (int k0 = 0; k0 < K; k0 += 16) {
            __syncthreads();
            float4 av = *(const float4*)(Ap + (size_t)(m0 + arow) * K + k0 + acol);
            As[acol + 0][arow] = av.x;
            As[acol + 1][arow] = av.y;
            As[acol + 2][arow] = av.z;
            As[acol + 3][arow] = av.w;
            *(float4*)&Ws[wrow][wcol] = *(const float4*)(Wp + (size_t)(k0 + wrow) * N + n0 + wcol);
            __syncthreads();
            #pragma unroll
            for (int kk = 0; kk < 16; ++kk) {
                float4 a4 = *(const float4*)&As[kk][ty * 4];
                float4 b4 = *(const float4*)&Ws[kk][tx * 4];
                float aa[4] = {a4.x, a4.y, a4.z, a4.w};
                float bb[4] = {b4.x, b4.y, b4.z, b4.w};
                #pragma unroll
                for (int i = 0; i < 4; ++i)
                    #pragma unroll
                    for (int j = 0; j < 4; ++j)
                        acc[i][j] += aa[i] * bb[j];
            }
        }
    }
    float4 bv = *(const float4*)(bias + n0 + tx * 4);
    float bb4[4] = {bv.x, bv.y, bv.z, bv.w};
    #pragma unroll
    for (int i = 0; i < 4; ++i) {
        float c[4];
        #pragma unroll
        for (int j = 0; j < 4; ++j) {
            c[j] = acc[i][j] + bb4[j];
            if (ACT == 1) c[j] = fmaxf(c[j], 0.f);
        }
        ushort4 ov;
        ov.x = f2bf(c[0]); ov.y = f2bf(c[1]); ov.z = f2bf(c[2]); ov.w = f2bf(c[3]);
        *(ushort4*)(Cb + (size_t)(m0 + ty * 4 + i) * N + n0 + tx * 4) = ov;
    }
}

// ---------------------------------------------------------------- bf16 MFMA GEMM (m97 recipe)
template <int ACT, bool DUAL, bool OUTF32, bool OUTBF16>
__global__ __launch_bounds__(256) void mfma_gemm_kernel(
    const unsigned short* __restrict__ A,  const unsigned short* __restrict__ Wt,
    const unsigned short* __restrict__ A2, const unsigned short* __restrict__ Wt2,
    const float* __restrict__ bias, float* __restrict__ Cf,
    unsigned short* __restrict__ Cb, int M, int N, int K)
{
    __shared__ __align__(16) unsigned short As[128 * 32];
    __shared__ __align__(16) unsigned short Bs[128 * 32];
    const int t = threadIdx.x;
    const int wave = t >> 6, lane = t & 63;
    const int quad = lane >> 4, r16 = lane & 15;
    const int wr = (wave >> 1) * 64, wc = (wave & 1) * 64;
    const int m0 = blockIdx.y * 128, n0 = blockIdx.x * 128;
    const int srow = t >> 2, sq = (t & 3) * 8;

    unsigned short* la = As + wave * 512;
    unsigned short* lb = Bs + wave * 512;

    f32x4 acc[4][4];
    #pragma unroll
    for (int i = 0; i < 4; ++i)
        #pragma unroll
        for (int j = 0; j < 4; ++j)
            acc[i][j] = (f32x4){0.f, 0.f, 0.f, 0.f};

    const int npass = DUAL ? 2 : 1;
    for (int pass = 0; pass < npass; ++pass) {
        const unsigned short* Ap = (DUAL && pass) ? A2 : A;
        const unsigned short* Wp = (DUAL && pass) ? Wt2 : Wt;
        for (int k0 = 0; k0 < K; k0 += 32) {
            __syncthreads();
            gl_lds16(&Ap[(size_t)(m0 + srow) * K + k0 + sq],       la);
            gl_lds16(&Ap[(size_t)(m0 + 64 + srow) * K + k0 + sq],  la + 2048);
            gl_lds16(&Wp[(size_t)(n0 + srow) * K + k0 + sq],       lb);
            gl_lds16(&Wp[(size_t)(n0 + 64 + srow) * K + k0 + sq],  lb + 2048);
            __syncthreads();
            bf16x8 af[4], bfr[4];
            #pragma unroll
            for (int i = 0; i < 4; ++i)
                af[i] = *(const bf16x8*)&As[(wr + i * 16 + r16) * 32 + quad * 8];
            #pragma unroll
            for (int j = 0; j < 4; ++j)
                bfr[j] = *(const bf16x8*)&Bs[(wc + j * 16 + r16) * 32 + quad * 8];
            #pragma unroll
            for (int i = 0; i < 4; ++i)
                #pragma unroll
                for (int j = 0; j < 4; ++j)
                    acc[i][j] = __builtin_amdgcn_mfma_f32_16x16x32_bf16(
                        af[i], bfr[j], acc[i][j], 0, 0, 0);
        }
    }

    float bcol[4];
    #pragma unroll
    for (int j = 0; j < 4; ++j) bcol[j] = bias[n0 + wc + j * 16 + r16];
    #pragma unroll
    for (int i = 0; i < 4; ++i) {
        const int rowb = m0 + wr + i * 16 + quad * 4;
        #pragma unroll
        for (int rr = 0; rr < 4; ++rr) {
            const size_t rb = (size_t)(rowb + rr) * N;
            #pragma unroll
            for (int j = 0; j < 4; ++j) {
                float v = acc[i][j][rr] + bcol[j];
                if (ACT == 1) v = fmaxf(v, 0.f);
                const int col = n0 + wc + j * 16 + r16;
                if (OUTF32) Cf[rb + col] = v;
                if (OUTBF16) Cb[rb + col] = f2bf(v);
            }
        }
    }
}

// ---------------------------------------------------------------- QKV GEMM: Q,K row-major -> QKb[NR][512];
// V blocks (n0>=512) store V^T directly: Vt[g][dim][key].
__global__ __launch_bounds__(256) void gemm_qkv_kernel(
    const unsigned short* __restrict__ A, const unsigned short* __restrict__ Wt,
    const float* __restrict__ bias, unsigned short* __restrict__ QKb,
    unsigned short* __restrict__ Vt, int K)
{
    __shared__ __align__(16) unsigned short As[128 * 32];
    __shared__ __align__(16) unsigned short Bs[128 * 32];
    const int t = threadIdx.x;
    const int wave = t >> 6, lane = t & 63;
    const int quad = lane >> 4, r16 = lane & 15;
    const int wr = (wave >> 1) * 64, wc = (wave & 1) * 64;
    const int m0 = blockIdx.y * 128, n0 = blockIdx.x * 128;
    const int srow = t >> 2, sq = (t & 3) * 8;
    unsigned short* la = As + wave * 512;
    unsigned short* lb = Bs + wave * 512;

    f32x4 acc[4][4];
    #pragma unroll
    for (int i = 0; i < 4; ++i)
        #pragma unroll
        for (int j = 0; j < 4; ++j)
            acc[i][j] = (f32x4){0.f, 0.f, 0.f, 0.f};

    for (int k0 = 0; k0 < K; k0 += 32) {
        __syncthreads();
        gl_lds16(&A[(size_t)(m0 + srow) * K + k0 + sq],       la);
        gl_lds16(&A[(size_t)(m0 + 64 + srow) * K + k0 + sq],  la + 2048);
        gl_lds16(&Wt[(size_t)(n0 + srow) * K + k0 + sq],      lb);
        gl_lds16(&Wt[(size_t)(n0 + 64 + srow) * K + k0 + sq], lb + 2048);
        __syncthreads();
        bf16x8 af[4], bfr[4];
        #pragma unroll
        for (int i = 0; i < 4; ++i)
            af[i] = *(const bf16x8*)&As[(wr + i * 16 + r16) * 32 + quad * 8];
        #pragma unroll
        for (int j = 0; j < 4; ++j)
            bfr[j] = *(const bf16x8*)&Bs[(wc + j * 16 + r16) * 32 + quad * 8];
        #pragma unroll
        for (int i = 0; i < 4; ++i)
            #pragma unroll
            for (int j = 0; j < 4; ++j)
                acc[i][j] = __builtin_amdgcn_mfma_f32_16x16x32_bf16(
                    af[i], bfr[j], acc[i][j], 0, 0, 0);
    }

    float bcol[4];
    #pragma unroll
    for (int j = 0; j < 4; ++j) bcol[j] = bias[n0 + wc + j * 16 + r16];

    if (n0 < 512) {
        #pragma unroll
        for (int i = 0; i < 4; ++i) {
            const int rowb = m0 + wr + i * 16 + quad * 4;
            #pragma unroll
            for (int rr = 0; rr < 4; ++rr) {
                const size_t rb = (size_t)(rowb + rr) * QKW;
                #pragma unroll
                for (int j = 0; j < 4; ++j)
                    QKb[rb + n0 + wc + j * 16 + r16] = f2bf(acc[i][j][rr] + bcol[j]);
            }
        }
    } else {
        #pragma unroll
        for (int i = 0; i < 4; ++i) {
            const int rowb = m0 + wr + i * 16 + quad * 4;
            const int g = rowb / LM;
            const int key = rowb - g * LM;
            #pragma unroll
            for (int j = 0; j < 4; ++j) {
                const int dim = n0 - 512 + wc + j * 16 + r16;
                unsigned short pk[4];
                #pragma unroll
                for (int rr = 0; rr < 4; ++rr) pk[rr] = f2bf(acc[i][j][rr] + bcol[j]);
                *(uint2*)&Vt[((size_t)g * DD + dim) * LM + key] = *(uint2*)pk;
            }
        }
    }
}

// ---------------------------------------------------------------- GEMM + residual + LayerNorm fused
// 32 rows x 256 cols, 4 waves = 4 col slabs, grid NR/32.
template <bool PERM>
__global__ __launch_bounds__(256) void gemm_ln_kernel(
    const unsigned short* __restrict__ A, const unsigned short* __restrict__ Wt,
    const float* __restrict__ bias, const float* __restrict__ resid,
    const float* __restrict__ gam, const float* __restrict__ bet,
    float* __restrict__ outHf, unsigned short* __restrict__ outHb, int K)
{
    __shared__ __align__(16) unsigned short As[32 * 32];
    __shared__ __align__(16) unsigned short Bs[256 * 32];
    __shared__ float red[2][4][32];
    const int t = threadIdx.x;
    const int wave = t >> 6, lane = t & 63;
    const int quad = lane >> 4, r16 = lane & 15;
    const int wc = wave * 64;
    const int m0 = blockIdx.x * 32;
    const int sr = lane >> 2, sq = (lane & 3) * 8;

    f32x4 acc[2][4];
    #pragma unroll
    for (int i = 0; i < 2; ++i)
        #pragma unroll
        for (int j = 0; j < 4; ++j)
            acc[i][j] = (f32x4){0.f, 0.f, 0.f, 0.f};

    for (int k0 = 0; k0 < K; k0 += 32) {
        __syncthreads();
        if (wave < 2)
            gl_lds16(&A[(size_t)(m0 + wave * 16 + sr) * K + k0 + sq], As + wave * 512);
        #pragma unroll
        for (int c = 0; c < 4; ++c)
            gl_lds16(&Wt[(size_t)(wc + c * 16 + sr) * K + k0 + sq],
                     Bs + wave * 2048 + c * 512);
        __syncthreads();
        bf16x8 af[2], bfr[4];
        #pragma unroll
        for (int i = 0; i < 2; ++i)
            af[i] = *(const bf16x8*)&As[(i * 16 + r16) * 32 + quad * 8];
        #pragma unroll
        for (int j = 0; j < 4; ++j)
            bfr[j] = *(const bf16x8*)&Bs[(wc + j * 16 + r16) * 32 + quad * 8];
        #pragma unroll
        for (int i = 0; i < 2; ++i)
            #pragma unroll
            for (int j = 0; j < 4; ++j)
                acc[i][j] = __builtin_amdgcn_mfma_f32_16x16x32_bf16(
                    af[i], bfr[j], acc[i][j], 0, 0, 0);
    }

    float bcol[4];
    #pragma unroll
    for (int j = 0; j < 4; ++j) bcol[j] = bias[wc + j * 16 + r16];

    #pragma unroll
    for (int i = 0; i < 2; ++i) {
        const int row = i * 16 + quad * 4;
        #pragma unroll
        for (int rr = 0; rr < 4; ++rr) {
            const size_t rb = (size_t)(m0 + row + rr) * DD;
            float s1 = 0.f, s2 = 0.f;
            #pragma unroll
            for (int j = 0; j < 4; ++j) {
                float v = acc[i][j][rr] + bcol[j] + resid[rb + wc + j * 16 + r16];
                acc[i][j][rr] = v;
                s1 += v;
                s2 += v * v;
            }
            #pragma unroll
            for (int off = 1; off < 16; off <<= 1) {
                s1 += __shfl_xor(s1, off, 64);
                s2 += __shfl_xor(s2, off, 64);
            }
            if (r16 == 0) {
                red[0][wave][row + rr] = s1;
                red[1][wave][row + rr] = s2;
            }
        }
    }
    __syncthreads();
    #pragma unroll
    for (int i = 0; i < 2; ++i) {
        const int row = i * 16 + quad * 4;
        #pragma unroll
        for (int rr = 0; rr < 4; ++rr) {
            const int gr = m0 + row + rr;
            float s1 = red[0][0][row + rr] + red[0][1][row + rr]
                     + red[0][2][row + rr] + red[0][3][row + rr];
            float s2 = red[1][0][row + rr] + red[1][1][row + rr]
                     + red[1][2][row + rr] + red[1][3][row + rr];
            float mean = s1 * (1.f / 256.f);
            float var  = s2 * (1.f / 256.f) - mean * mean;
            float rs = rsqrtf(var + 1e-5f);
            size_t fb;
            if (PERM) {
                int gg = gr / LM, pos = gr - gg * LM;
                fb = ((size_t)pos * NG + gg) * DD;
            } else {
                fb = (size_t)gr * DD;
            }
            const size_t hb = (size_t)gr * DD;
            #pragma unroll
            for (int j = 0; j < 4; ++j) {
                const int col = wc + j * 16 + r16;
                float ov = (acc[i][j][rr] - mean) * rs * gam[col] + bet[col];
                outHf[fb + col] = ov;
                outHb[hb + col] = f2bf(ov);
            }
        }
    }
}

// ---------------------------------------------------------------- pack to graph-major padded [g][pos][D]
__global__ __launch_bounds__(256) void pack_kernel(
    const float* __restrict__ z, const int* __restrict__ batches,
    float* __restrict__ Hf, unsigned short* __restrict__ Hb)
{
    int node = blockIdx.x * 4 + (threadIdx.x >> 6);
    int lane = threadIdx.x & 63;
    int lo = 0, hi = NG;
    while (lo < hi) {
        int mid = (lo + hi + 1) >> 1;
        if (batches[mid] <= node) lo = mid; else hi = mid - 1;
    }
    int pos = node - batches[lo];
    size_t base = ((size_t)lo * LM + pos) * DD + lane * 4;
    float4 zv = *(const float4*)(z + (size_t)node * DD + lane * 4);
    *(float4*)(Hf + base) = zv;
    ushort4 hb;
    hb.x = f2bf(zv.x); hb.y = f2bf(zv.y); hb.z = f2bf(zv.z); hb.w = f2bf(zv.w);
    *(ushort4*)(Hb + base) = hb;
}

// ---------------------------------------------------------------- MFMA flash attention (no barriers)
__global__ __launch_bounds__(256) void attn_mfma_kernel(
    const unsigned short* __restrict__ qk, const unsigned short* __restrict__ vt,
    const int* __restrict__ batches, unsigned short* __restrict__ o)
{
    __shared__ __align__(16) unsigned short Pa[4][32 * 40];
    const int bx = blockIdx.x;
    const int g = bx & 63;
    const int r = bx >> 6;            // 0..19
    const int q0 = (r >> 1) * 32;
    const int tid = threadIdx.x;
    const int wave = tid >> 6;
    const int h = (r & 1) * 4 + wave;
    const int lane = tid & 63;
    const int quad = lane >> 4, r16 = lane & 15;
    const int len = batches[g + 1] - batches[g];
    const size_t gq = (size_t)g * LM;
    unsigned short* pa = Pa[wave];

    bf16x8 qf[2];
    #pragma unroll
    for (int i = 0; i < 2; ++i)
        qf[i] = *(const bf16x8*)(qk + (gq + q0 + i * 16 + r16) * QKW + h * 32 + quad * 8);
    bf16x8 onesf;
    #pragma unroll
    for (int j = 0; j < 8; ++j) onesf[j] = (short)0x3F80;   // bf16 1.0

    f32x4 oacc[2][2], lacc[2];
    #pragma unroll
    for (int i = 0; i < 2; ++i) {
        lacc[i] = (f32x4){0.f, 0.f, 0.f, 0.f};
        #pragma unroll
        for (int nt = 0; nt < 2; ++nt)
            oacc[i][nt] = (f32x4){0.f, 0.f, 0.f, 0.f};
    }

    for (int t0 = 0; t0 < len; t0 += 32) {
        bf16x8 kf[2], vf[2];
        #pragma unroll
        for (int mt = 0; mt < 2; ++mt) {
            int kr = t0 + mt * 16 + r16; if (kr > LM - 1) kr = LM - 1;
            kf[mt] = *(const bf16x8*)(qk + (gq + kr) * QKW + 256 + h * 32 + quad * 8);
        }
        #pragma unroll
        for (int nt = 0; nt < 2; ++nt)
            vf[nt] = *(const bf16x8*)(vt + ((size_t)g * DD + h * 32 + nt * 16 + r16) * LM
                                      + t0 + quad * 8);
        f32x4 st[2][2];
        #pragma unroll
        for (int mt = 0; mt < 2; ++mt)
            #pragma unroll
            for (int i = 0; i < 2; ++i)
                st[mt][i] = (f32x4){0.f, 0.f, 0.f, 0.f};
        #pragma unroll
        for (int mt = 0; mt < 2; ++mt)
            #pragma unroll
            for (int i = 0; i < 2; ++i)
                st[mt][i] = __builtin_amdgcn_mfma_f32_16x16x32_bf16(
                    kf[mt], qf[i], st[mt][i], 0, 0, 0);
        #pragma unroll
        for (int i = 0; i < 2; ++i) {
            #pragma unroll
            for (int mt = 0; mt < 2; ++mt) {
                float pr[4];
                #pragma unroll
                for (int rr = 0; rr < 4; ++rr) {
                    int key = t0 + mt * 16 + quad * 4 + rr;
                    pr[rr] = (key < len) ? __expf(st[mt][i][rr]) : 0.f;
                }
                uint2 w;
                w.x = ((unsigned)f2bf(pr[1]) << 16) | f2bf(pr[0]);
                w.y = ((unsigned)f2bf(pr[3]) << 16) | f2bf(pr[2]);
                *(uint2*)&pa[(i * 16 + r16) * 40 + mt * 16 + quad * 4] = w;
            }
        }
        __asm__ volatile("s_waitcnt lgkmcnt(0)" ::: "memory");
        bf16x8 pf[2];
        #pragma unroll
        for (int i = 0; i < 2; ++i)
            pf[i] = *(const bf16x8*)&pa[(i * 16 + r16) * 40 + quad * 8];
        #pragma unroll
        for (int i = 0; i < 2; ++i) {
            #pragma unroll
            for (int nt = 0; nt < 2; ++nt)
                oacc[i][nt] = __builtin_amdgcn_mfma_f32_16x16x32_bf16(
                    pf[i], vf[nt], oacc[i][nt], 0, 0, 0);
            lacc[i] = __builtin_amdgcn_mfma_f32_16x16x32_bf16(
                pf[i], onesf, lacc[i], 0, 0, 0);
        }
    }
    #pragma unroll
    for (int i = 0; i < 2; ++i) {
        #pragma unroll
        for (int rr = 0; rr < 4; ++rr) {
            float inv = 1.f / lacc[i][rr];
            size_t base = (gq + q0 + i * 16 + quad * 4 + rr) * DD + h * 32;
            #pragma unroll
            for (int nt = 0; nt < 2; ++nt)
                o[base + nt * 16 + r16] = f2bf(oacc[i][nt][rr] * inv);
        }
    }
}

// ---------------------------------------------------------------- launcher
extern "C" void kernel_launch(void* const* d_in, const int* in_sizes, int n_in,
                              void* d_out, int out_size, void* d_ws, size_t ws_size,
                              hipStream_t stream) {
    const float* x       = (const float*)d_in[0];
    const int*   ei      = (const int*)d_in[1];
    const int*   batches = (const int*)d_in[2];
    const float* sW0  = (const float*)d_in[4];
    const float* sWn0 = (const float*)d_in[5];
    const float* sb0  = (const float*)d_in[6];
    const float* sW1  = (const float*)d_in[7];
    const float* sWn1 = (const float*)d_in[8];
    const float* sb1  = (const float*)d_in[9];
    const float* sW2  = (const float*)d_in[10];
    const float* sWn2 = (const float*)d_in[11];
    const float* sb2  = (const float*)d_in[12];
    const float* Wq   = (const float*)d_in[13];
    const float* Wk   = (const float*)d_in[14];
    const float* Wv   = (const float*)d_in[15];
    const float* bq   = (const float*)d_in[16];
    const float* bk   = (const float*)d_in[17];
    const float* bv   = (const float*)d_in[18];
    const float* Wo   = (const float*)d_in[19];
    const float* bo   = (const float*)d_in[20];
    const float* ln1g = (const float*)d_in[21];
    const float* ln1b = (const float*)d_in[22];
    const float* ln2g = (const float*)d_in[23];
    const float* ln2b = (const float*)d_in[24];
    const float* W1   = (const float*)d_in[25];
    const float* b1   = (const float*)d_in[26];
    const float* W2   = (const float*)d_in[27];
    const float* b2   = (const float*)d_in[28];

    char* p = (char*)d_ws;
    auto alloc = [&](size_t bytes) {
        char* r = p;
        p += (bytes + 255) & ~(size_t)255;
        return r;
    };
    int*   counts  = (int*)alloc((size_t)NN * 4);
    int*   offsets = (int*)alloc((size_t)(NN + 1) * 4);
    int*   cursor  = (int*)alloc((size_t)NN * 4);
    int*   csr     = (int*)alloc((size_t)NE * 4);
    float* agg0    = (float*)alloc((size_t)NN * CIN * 4);
    unsigned short* z0b = (unsigned short*)alloc((size_t)NN * DD * 2);
    unsigned short* a1b = (unsigned short*)alloc((size_t)NN * DD * 2);
    unsigned short* z1b = (unsigned short*)alloc((size_t)NN * DD * 2);
    unsigned short* a2b = (unsigned short*)alloc((size_t)NN * DD * 2);
    float* z2f     = (float*)alloc((size_t)NN * DD * 4);   // dead after pack -> Vt aliases it
    unsigned short* Vt = (unsigned short*)z2f;             // [64][256][320] bf16 = 10.5 MB
    float* Hf      = (float*)alloc((size_t)NR * DD * 4);
    unsigned short* Hb = (unsigned short*)alloc((size_t)NR * DD * 2);
    unsigned short* Ob = (unsigned short*)alloc((size_t)NR * DD * 2);
    float* R       = (float*)alloc((size_t)NR * DFF * 2);  // QKb / F1b alias region (40 MB)
    unsigned short* QKb = (unsigned short*)R;              // [NR][512] bf16 = 21 MB
    unsigned short* F1b = (unsigned short*)R;              // [NR][1024] bf16 = 40 MB
    unsigned short* Wqkvt = (unsigned short*)alloc((size_t)NLY * QS * DD * 2);
    unsigned short* Wot   = (unsigned short*)alloc((size_t)NLY * DD * DD * 2);
    unsigned short* W1t   = (unsigned short*)alloc((size_t)NLY * DFF * DD * 2);
    unsigned short* W2t   = (unsigned short*)alloc((size_t)NLY * DD * DFF * 2);
    unsigned short* sW1t  = (unsigned short*)alloc((size_t)DD * DD * 2);
    unsigned short* sWn1t = (unsigned short*)alloc((size_t)DD * DD * 2);
    unsigned short* sW2t  = (unsigned short*)alloc((size_t)DD * DD * 2);
    unsigned short* sWn2t = (unsigned short*)alloc((size_t)DD * DD * 2);
    float* bqkvp   = (float*)alloc((size_t)NLY * QS * 4);

    // ---- weight prep (tiled transpose) ----
    prep_qkv2_kernel<<<dim3(QS / 64, DD / 64, NLY), 256, 0, stream>>>(Wq, Wk, Wv, Wqkvt);
    prep_t2_kernel<<<dim3(DD / 64, DD / 64, NLY), 256, 0, stream>>>(Wo, Wot, DD, DD);
    prep_t2_kernel<<<dim3(DFF / 64, DD / 64, NLY), 256, 0, stream>>>(W1, W1t, DD, DFF);
    prep_t2_kernel<<<dim3(DD / 64, DFF / 64, NLY), 256, 0, stream>>>(W2, W2t, DFF, DD);
    prep_t2_kernel<<<dim3(DD / 64, DD / 64, 1), 256, 0, stream>>>(sW1, sW1t, DD, DD);
    prep_t2_kernel<<<dim3(DD / 64, DD / 64, 1), 256, 0, stream>>>(sWn1, sWn1t, DD, DD);
    prep_t2_kernel<<<dim3(DD / 64, DD / 64, 1), 256, 0, stream>>>(sW2, sW2t, DD, DD);
    prep_t2_kernel<<<dim3(DD / 64, DD / 64, 1), 256, 0, stream>>>(sWn2, sWn2t, DD, DD);
    prep_bias_kernel<<<(NLY * QS + 255) / 256, 256, 0, stream>>>(bq, bk, bv, bqkvp);

    // ---- CSR build ----
    zero_int_kernel<<<NN / 256, 256, 0, stream>>>(counts, NN);
    count_edges_kernel<<<NE / 256, 256, 0, stream>>>(ei + NE, counts);
    scan_kernel<<<1, 256, 0, stream>>>(counts, offsets, cursor);
    fill_csr_kernel<<<NE / 256, 256, 0, stream>>>(ei, ei + NE, cursor, csr);

    // ---- SAGE ----
    agg_mean16_kernel<<<NN / 16, 256, 0, stream>>>(x, offsets, csr, agg0);
    gemm_f32b_kernel<1, true><<<dim3(DD / 64, NN / 64), 256, 0, stream>>>(
        x, sW0, agg0, sWn0, sb0, z0b, NN, DD, CIN);
    agg_mean_b_kernel<<<NN / 4, 256, 0, stream>>>(z0b, offsets, csr, a1b);
    mfma_gemm_kernel<1, true, false, true><<<dim3(DD / 128, NN / 128), 256, 0, stream>>>(
        z0b, sW1t, a1b, sWn1t, sb1, nullptr, z1b, NN, DD, DD);
    agg_mean_b_kernel<<<NN / 4, 256, 0, stream>>>(z1b, offsets, csr, a2b);
    mfma_gemm_kernel<0, true, true, false><<<dim3(DD / 128, NN / 128), 256, 0, stream>>>(
        z1b, sW2t, a2b, sWn2t, sb2, z2f, nullptr, NN, DD, DD);

    // ---- pack (graph-major) ----
    zero_f4_kernel<<<((size_t)NR * DD / 4) / 256, 256, 0, stream>>>((float4*)Hf, NR * DD / 4);
    zero_f4_kernel<<<((size_t)NR * DD / 8) / 256, 256, 0, stream>>>((float4*)Hb, NR * DD / 8);
    pack_kernel<<<NN / 4, 256, 0, stream>>>(z2f, batches, Hf, Hb);

    // ---- transformer ----
    for (int l = 0; l < NLY; ++l) {
        gemm_qkv_kernel<<<dim3(QS / 128, NR / 128), 256, 0, stream>>>(
            Hb, Wqkvt + (size_t)l * QS * DD, bqkvp + (size_t)l * QS, QKb, Vt, DD);
        attn_mfma_kernel<<<NG * 20, 256, 0, stream>>>(QKb, Vt, batches, Ob);
        gemm_ln_kernel<false><<<NR / 32, 256, 0, stream>>>(
            Ob, Wot + (size_t)l * DD * DD, bo + (size_t)l * DD, Hf,
            ln1g + (size_t)l * DD, ln1b + (size_t)l * DD, Hf, Hb, DD);
        mfma_gemm_kernel<1, false, false, true><<<dim3(DFF / 128, NR / 128), 256, 0, stream>>>(
            Hb, W1t + (size_t)l * DFF * DD, nullptr, nullptr,
            b1 + (size_t)l * DFF, nullptr, F1b, NR, DFF, DD);
        if (l == NLY - 1)
            gemm_ln_kernel<true><<<NR / 32, 256, 0, stream>>>(
                F1b, W2t + (size_t)l * DD * DFF, b2 + (size_t)l * DD, Hf,
                ln2g + (size_t)l * DD, ln2b + (size_t)l * DD, (float*)d_out, Hb, DFF);
        else
            gemm_ln_kernel<false><<<NR / 32, 256, 0, stream>>>(
                F1b, W2t + (size_t)l * DD * DFF, b2 + (size_t)l * DD, Hf,
                ln2g + (size_t)l * DD, ln2b + (size_t)l * DD, Hf, Hb, DFF);
    }
}

// Round 10
// 802.783 us; speedup vs baseline: 1.2160x; 1.0551x over previous
//
#include <hip/hip_runtime.h>
#include <hip/hip_bf16.h>
#include <math.h>

#define NN  16384      // nodes
#define NE  262144     // edges
#define NG  64         // graphs
#define CIN 16         // input colors
#define DD  256        // embedding
#define NHD 8          // heads
#define DHD 32         // head dim
#define DFF 1024       // ffn dim
#define NLY 4          // layers
#define LM  320        // L_max
#define NR  (LM*NG)    // padded rows = 20480
#define QS  768        // fused QKV col count
#define QKW 512        // Q|K row stride in QKb

typedef __attribute__((ext_vector_type(8))) short bf16x8;
typedef __attribute__((ext_vector_type(4))) float f32x4;

__device__ __forceinline__ unsigned short f2bf(float f) {
    union { __hip_bfloat16 h; unsigned short u; } cv;
    cv.h = __float2bfloat16(f);
    return cv.u;
}
__device__ __forceinline__ float bf2f(unsigned short u) {
    return __uint_as_float((unsigned int)u << 16);
}
// async global->LDS 16B: dest = wave-uniform lds base + lane*16
__device__ __forceinline__ void gl_lds16(const unsigned short* g, unsigned short* l) {
    __builtin_amdgcn_global_load_lds(
        (const __attribute__((address_space(1))) unsigned int*)g,
        (__attribute__((address_space(3))) unsigned int*)l, 16, 0, 0);
}

// ---------------------------------------------------------------- zero (Hb pad + CSR counts), one dispatch
__global__ void zero_ws_kernel(uint4* __restrict__ hb, int n16, int* __restrict__ counts) {
    int i = blockIdx.x * 256 + threadIdx.x;
    if (i < n16) hb[i] = (uint4){0u, 0u, 0u, 0u};
    if (i < NN) counts[i] = 0;
}

// ---------------------------------------------------------------- fused weight prep (one dispatch, 844 blocks)
// Segments: [0,12) bias; [12,204) QKV; [204,268) Wo; [268,524) W1; [524,780) W2; [780,844) SAGE x4.
__global__ __launch_bounds__(256) void prep_all_kernel(
    const float* __restrict__ Wq, const float* __restrict__ Wk, const float* __restrict__ Wv,
    const float* __restrict__ Wo, const float* __restrict__ W1, const float* __restrict__ W2,
    const float* __restrict__ sW1, const float* __restrict__ sWn1,
    const float* __restrict__ sW2, const float* __restrict__ sWn2,
    const float* __restrict__ bq, const float* __restrict__ bk, const float* __restrict__ bv,
    unsigned short* __restrict__ Wqkvt, unsigned short* __restrict__ Wot,
    unsigned short* __restrict__ W1t, unsigned short* __restrict__ W2t,
    unsigned short* __restrict__ sW1t, unsigned short* __restrict__ sWn1t,
    unsigned short* __restrict__ sW2t, unsigned short* __restrict__ sWn2t,
    float* __restrict__ bqkvp)
{
    const int t = threadIdx.x;
    int bid = blockIdx.x;
    if (bid < 12) {                      // fused QKV bias (scale folded into Q)
        int i = bid * 256 + t;
        if (i < NLY * QS) {
            int n = i % QS, l = i / QS;
            const float* b = (n < 256) ? bq : (n < 512 ? bk : bv);
            float v = b[l * DD + (n & 255)];
            if (n < 256) v *= 0.17677669529663687f;
            bqkvp[i] = v;
        }
        return;
    }
    bid -= 12;
    __shared__ float Ls[64][68];
    const float* inP;
    unsigned short* outP;
    int strideIn, strideOut;
    float sc = 1.f;
    if (bid < 192) {                     // QKV weights
        int x = bid % 12, y = (bid / 12) % 4, l = bid / 48;
        int n0 = x * 64, k0 = y * 64;
        const float* W = (n0 < 256) ? Wq : (n0 < 512 ? Wk : Wv);
        if (n0 < 256) sc = 0.17677669529663687f;
        inP  = W + ((size_t)l * DD + k0) * DD + (n0 & 255);
        strideIn = DD;
        outP = Wqkvt + ((size_t)l * QS + n0) * DD + k0;
        strideOut = DD;
    } else if (bid < 192 + 64) {         // Wo
        bid -= 192;
        int x = bid % 4, y = (bid / 4) % 4, l = bid / 16;
        int n0 = x * 64, k0 = y * 64;
        inP  = Wo + ((size_t)l * DD + k0) * DD + n0;
        strideIn = DD;
        outP = Wot + ((size_t)l * DD + n0) * DD + k0;
        strideOut = DD;
    } else if (bid < 192 + 64 + 256) {   // W1: [DD][DFF] -> [DFF][DD]
        bid -= 192 + 64;
        int x = bid % 16, y = (bid / 16) % 4, l = bid / 64;
        int n0 = x * 64, k0 = y * 64;
        inP  = W1 + ((size_t)l * DD + k0) * DFF + n0;
        strideIn = DFF;
        outP = W1t + ((size_t)l * DFF + n0) * DD + k0;
        strideOut = DD;
    } else if (bid < 192 + 64 + 512) {   // W2: [DFF][DD] -> [DD][DFF]
        bid -= 192 + 64 + 256;
        int x = bid % 4, y = (bid / 4) % 16, l = bid / 64;
        int n0 = x * 64, k0 = y * 64;
        inP  = W2 + ((size_t)l * DFF + k0) * DD + n0;
        strideIn = DD;
        outP = W2t + ((size_t)l * DD + n0) * DFF + k0;
        strideOut = DFF;
    } else {                             // SAGE weights (4 x 16 tiles)
        bid -= 192 + 64 + 512;
        int w = bid / 16, r = bid % 16;
        int x = r % 4, y = r / 4;
        int n0 = x * 64, k0 = y * 64;
        const float* src = (w == 0) ? sW1 : (w == 1) ? sWn1 : (w == 2) ? sW2 : sWn2;
        unsigned short* dst = (w == 0) ? sW1t : (w == 1) ? sWn1t : (w == 2) ? sW2t : sWn2t;
        inP  = src + (size_t)k0 * DD + n0;
        strideIn = DD;
        outP = dst + (size_t)n0 * DD + k0;
        strideOut = DD;
    }
    #pragma unroll
    for (int it = 0; it < 4; ++it) {
        int lin = it * 256 + t;
        int kr = lin >> 4, nc = (lin & 15) * 4;
        float4 v = *(const float4*)&inP[(size_t)kr * strideIn + nc];
        Ls[kr][nc]     = v.x * sc;
        Ls[kr][nc + 1] = v.y * sc;
        Ls[kr][nc + 2] = v.z * sc;
        Ls[kr][nc + 3] = v.w * sc;
    }
    __syncthreads();
    #pragma unroll
    for (int it = 0; it < 2; ++it) {
        int lin = it * 256 + t;
        int nr = lin >> 3, kc = (lin & 7) * 8;
        unsigned short pk[8];
        #pragma unroll
        for (int j = 0; j < 8; ++j) pk[j] = f2bf(Ls[kc + j][nr]);
        *(uint4*)&outP[(size_t)nr * strideOut + kc] = *(uint4*)pk;
    }
}

// ---------------------------------------------------------------- CSR build
__global__ void count_edges_kernel(const int* __restrict__ dst, int* __restrict__ counts) {
    int e = blockIdx.x * 256 + threadIdx.x;
    if (e < NE) atomicAdd(&counts[dst[e]], 1);
}

__global__ __launch_bounds__(256) void scan_kernel(const int* __restrict__ counts,
                                                   int* __restrict__ offsets,
                                                   int* __restrict__ cursor) {
    __shared__ int part[256];
    int t = threadIdx.x;
    int base = t * 64;
    int s = 0;
    for (int i = 0; i < 64; ++i) s += counts[base + i];
    part[t] = s;
    __syncthreads();
    for (int off = 1; off < 256; off <<= 1) {
        int val = (t >= off) ? part[t - off] : 0;
        __syncthreads();
        part[t] += val;
        __syncthreads();
    }
    int run = (t == 0) ? 0 : part[t - 1];
    for (int i = 0; i < 64; ++i) {
        offsets[base + i] = run;
        cursor[base + i]  = run;
        run += counts[base + i];
    }
    if (t == 255) offsets[NN] = run;
}

__global__ void fill_csr_kernel(const int* __restrict__ src, const int* __restrict__ dst,
                                int* __restrict__ cursor, int* __restrict__ csr) {
    int e = blockIdx.x * 256 + threadIdx.x;
    if (e < NE) {
        int p = atomicAdd(&cursor[dst[e]], 1);
        csr[p] = src[e];
    }
}

// ---------------------------------------------------------------- mean aggregation
__global__ __launch_bounds__(256) void agg_mean16_kernel(
    const float* __restrict__ h, const int* __restrict__ offsets,
    const int* __restrict__ csr, float* __restrict__ out)
{
    int node = blockIdx.x * 16 + (threadIdx.x >> 4);
    int d = threadIdx.x & 15;
    int beg = offsets[node], end = offsets[node + 1];
    float acc = 0.f;
    for (int e = beg; e < end; ++e) acc += h[(size_t)csr[e] * CIN + d];
    int dg = end - beg; if (dg < 1) dg = 1;
    out[(size_t)node * CIN + d] = acc * (1.f / (float)dg);
}

__global__ __launch_bounds__(256) void agg_mean_b_kernel(
    const unsigned short* __restrict__ h, const int* __restrict__ offsets,
    const int* __restrict__ csr, unsigned short* __restrict__ out)
{
    int node = blockIdx.x * 4 + (threadIdx.x >> 6);
    int lane = threadIdx.x & 63;
    int beg = offsets[node], end = offsets[node + 1];
    float a0 = 0.f, a1 = 0.f, a2 = 0.f, a3 = 0.f;
    for (int e = beg; e < end; ++e) {
        const ushort4 hv = *(const ushort4*)(h + (size_t)csr[e] * DD + lane * 4);
        a0 += bf2f(hv.x); a1 += bf2f(hv.y); a2 += bf2f(hv.z); a3 += bf2f(hv.w);
    }
    int dg = end - beg; if (dg < 1) dg = 1;
    float inv = 1.f / (float)dg;
    ushort4 ov;
    ov.x = f2bf(a0 * inv); ov.y = f2bf(a1 * inv);
    ov.z = f2bf(a2 * inv); ov.w = f2bf(a3 * inv);
    *(ushort4*)(out + (size_t)node * DD + lane * 4) = ov;
}

// ---------------------------------------------------------------- f32 tiled GEMM (SAGE layer0, K=16) -> bf16 out
template <int ACT, bool DUAL>
__global__ __launch_bounds__(256) void gemm_f32b_kernel(
    const float* __restrict__ A, const float* __restrict__ W,
    const float* __restrict__ A2, const float* __restrict__ W2,
    const float* __restrict__ bias, unsigned short* __restrict__ Cb,
    int M, int N, int K)
{
    __shared__ __align__(16) float As[16][64];
    __shared__ __align__(16) float Ws[16][64];
    const int t  = threadIdx.x;
    const int tx = t & 15, ty = t >> 4;
    const int m0 = blockIdx.y * 64, n0 = blockIdx.x * 64;
    const int arow = t >> 2, acol = (t & 3) * 4;
    const int wrow = t >> 4, wcol = (t & 15) * 4;
    float acc[4][4] = {};
    const int npass = DUAL ? 2 : 1;
    for (int pass = 0; pass < npass; ++pass) {
        const float* Ap = (DUAL && pass) ? A2 : A;
        const float* Wp = (DUAL && pass) ? W2 : W;
        for (int k0 = 0; k0 < K; k0 += 16) {
            __syncthreads();
            float4 av = *(const float4*)(Ap + (size_t)(m0 + arow) * K + k0 + acol);
            As[acol + 0][arow] = av.x;
            As[acol + 1][arow] = av.y;
            As[acol + 2][arow] = av.z;
            As[acol + 3][arow] = av.w;
            *(float4*)&Ws[wrow][wcol] = *(const float4*)(Wp + (size_t)(k0 + wrow) * N + n0 + wcol);
            __syncthreads();
            #pragma unroll
            for (int kk = 0; kk < 16; ++kk) {
                float4 a4 = *(const float4*)&As[kk][ty * 4];
                float4 b4 = *(const float4*)&Ws[kk][tx * 4];
                float aa[4] = {a4.x, a4.y, a4.z, a4.w};
                float bb[4] = {b4.x, b4.y, b4.z, b4.w};
                #pragma unroll
                for (int i = 0; i < 4; ++i)
                    #pragma unroll
                    for (int j = 0; j < 4; ++j)
                        acc[i][j] += aa[i] * bb[j];
            }
        }
    }
    float4 bv = *(const float4*)(bias + n0 + tx * 4);
    float bb4[4] = {bv.x, bv.y, bv.z, bv.w};
    #pragma unroll
    for (int i = 0; i < 4; ++i) {
        float c[4];
        #pragma unroll
        for (int j = 0; j < 4; ++j) {
            c[j] = acc[i][j] + bb4[j];
            if (ACT == 1) c[j] = fmaxf(c[j], 0.f);
        }
        ushort4 ov;
        ov.x = f2bf(c[0]); ov.y = f2bf(c[1]); ov.z = f2bf(c[2]); ov.w = f2bf(c[3]);
        *(ushort4*)(Cb + (size_t)(m0 + ty * 4 + i) * N + n0 + tx * 4) = ov;
    }
}

// ---------------------------------------------------------------- bf16 MFMA GEMM (m97 recipe)
template <int ACT, bool DUAL, bool OUTF32, bool OUTBF16>
__global__ __launch_bounds__(256) void mfma_gemm_kernel(
    const unsigned short* __restrict__ A,  const unsigned short* __restrict__ Wt,
    const unsigned short* __restrict__ A2, const unsigned short* __restrict__ Wt2,
    const float* __restrict__ bias, float* __restrict__ Cf,
    unsigned short* __restrict__ Cb, int M, int N, int K)
{
    __shared__ __align__(16) unsigned short As[128 * 32];
    __shared__ __align__(16) unsigned short Bs[128 * 32];
    const int t = threadIdx.x;
    const int wave = t >> 6, lane = t & 63;
    const int quad = lane >> 4, r16 = lane & 15;
    const int wr = (wave >> 1) * 64, wc = (wave & 1) * 64;
    const int m0 = blockIdx.y * 128, n0 = blockIdx.x * 128;
    const int srow = t >> 2, sq = (t & 3) * 8;

    unsigned short* la = As + wave * 512;
    unsigned short* lb = Bs + wave * 512;

    f32x4 acc[4][4];
    #pragma unroll
    for (int i = 0; i < 4; ++i)
        #pragma unroll
        for (int j = 0; j < 4; ++j)
            acc[i][j] = (f32x4){0.f, 0.f, 0.f, 0.f};

    const int npass = DUAL ? 2 : 1;
    for (int pass = 0; pass < npass; ++pass) {
        const unsigned short* Ap = (DUAL && pass) ? A2 : A;
        const unsigned short* Wp = (DUAL && pass) ? Wt2 : Wt;
        for (int k0 = 0; k0 < K; k0 += 32) {
            __syncthreads();
            gl_lds16(&Ap[(size_t)(m0 + srow) * K + k0 + sq],       la);
            gl_lds16(&Ap[(size_t)(m0 + 64 + srow) * K + k0 + sq],  la + 2048);
            gl_lds16(&Wp[(size_t)(n0 + srow) * K + k0 + sq],       lb);
            gl_lds16(&Wp[(size_t)(n0 + 64 + srow) * K + k0 + sq],  lb + 2048);
            __syncthreads();
            bf16x8 af[4], bfr[4];
            #pragma unroll
            for (int i = 0; i < 4; ++i)
                af[i] = *(const bf16x8*)&As[(wr + i * 16 + r16) * 32 + quad * 8];
            #pragma unroll
            for (int j = 0; j < 4; ++j)
                bfr[j] = *(const bf16x8*)&Bs[(wc + j * 16 + r16) * 32 + quad * 8];
            #pragma unroll
            for (int i = 0; i < 4; ++i)
                #pragma unroll
                for (int j = 0; j < 4; ++j)
                    acc[i][j] = __builtin_amdgcn_mfma_f32_16x16x32_bf16(
                        af[i], bfr[j], acc[i][j], 0, 0, 0);
        }
    }

    float bcol[4];
    #pragma unroll
    for (int j = 0; j < 4; ++j) bcol[j] = bias[n0 + wc + j * 16 + r16];
    #pragma unroll
    for (int i = 0; i < 4; ++i) {
        const int rowb = m0 + wr + i * 16 + quad * 4;
        #pragma unroll
        for (int rr = 0; rr < 4; ++rr) {
            const size_t rb = (size_t)(rowb + rr) * N;
            #pragma unroll
            for (int j = 0; j < 4; ++j) {
                float v = acc[i][j][rr] + bcol[j];
                if (ACT == 1) v = fmaxf(v, 0.f);
                const int col = n0 + wc + j * 16 + r16;
                if (OUTF32) Cf[rb + col] = v;
                if (OUTBF16) Cb[rb + col] = f2bf(v);
            }
        }
    }
}

// ---------------------------------------------------------------- QKV GEMM: Q,K row-major -> QKb[NR][512];
// V blocks (n0>=512) store V^T directly: Vt[g][dim][key].
__global__ __launch_bounds__(256) void gemm_qkv_kernel(
    const unsigned short* __restrict__ A, const unsigned short* __restrict__ Wt,
    const float* __restrict__ bias, unsigned short* __restrict__ QKb,
    unsigned short* __restrict__ Vt, int K)
{
    __shared__ __align__(16) unsigned short As[128 * 32];
    __shared__ __align__(16) unsigned short Bs[128 * 32];
    const int t = threadIdx.x;
    const int wave = t >> 6, lane = t & 63;
    const int quad = lane >> 4, r16 = lane & 15;
    const int wr = (wave >> 1) * 64, wc = (wave & 1) * 64;
    const int m0 = blockIdx.y * 128, n0 = blockIdx.x * 128;
    const int srow = t >> 2, sq = (t & 3) * 8;
    unsigned short* la = As + wave * 512;
    unsigned short* lb = Bs + wave * 512;

    f32x4 acc[4][4];
    #pragma unroll
    for (int i = 0; i < 4; ++i)
        #pragma unroll
        for (int j = 0; j < 4; ++j)
            acc[i][j] = (f32x4){0.f, 0.f, 0.f, 0.f};

    for (int k0 = 0; k0 < K; k0 += 32) {
        __syncthreads();
        gl_lds16(&A[(size_t)(m0 + srow) * K + k0 + sq],       la);
        gl_lds16(&A[(size_t)(m0 + 64 + srow) * K + k0 + sq],  la + 2048);
        gl_lds16(&Wt[(size_t)(n0 + srow) * K + k0 + sq],      lb);
        gl_lds16(&Wt[(size_t)(n0 + 64 + srow) * K + k0 + sq], lb + 2048);
        __syncthreads();
        bf16x8 af[4], bfr[4];
        #pragma unroll
        for (int i = 0; i < 4; ++i)
            af[i] = *(const bf16x8*)&As[(wr + i * 16 + r16) * 32 + quad * 8];
        #pragma unroll
        for (int j = 0; j < 4; ++j)
            bfr[j] = *(const bf16x8*)&Bs[(wc + j * 16 + r16) * 32 + quad * 8];
        #pragma unroll
        for (int i = 0; i < 4; ++i)
            #pragma unroll
            for (int j = 0; j < 4; ++j)
                acc[i][j] = __builtin_amdgcn_mfma_f32_16x16x32_bf16(
                    af[i], bfr[j], acc[i][j], 0, 0, 0);
    }

    float bcol[4];
    #pragma unroll
    for (int j = 0; j < 4; ++j) bcol[j] = bias[n0 + wc + j * 16 + r16];

    if (n0 < 512) {
        #pragma unroll
        for (int i = 0; i < 4; ++i) {
            const int rowb = m0 + wr + i * 16 + quad * 4;
            #pragma unroll
            for (int rr = 0; rr < 4; ++rr) {
                const size_t rb = (size_t)(rowb + rr) * QKW;
                #pragma unroll
                for (int j = 0; j < 4; ++j)
                    QKb[rb + n0 + wc + j * 16 + r16] = f2bf(acc[i][j][rr] + bcol[j]);
            }
        }
    } else {
        #pragma unroll
        for (int i = 0; i < 4; ++i) {
            const int rowb = m0 + wr + i * 16 + quad * 4;
            const int g = rowb / LM;
            const int key = rowb - g * LM;
            #pragma unroll
            for (int j = 0; j < 4; ++j) {
                const int dim = n0 - 512 + wc + j * 16 + r16;
                unsigned short pk[4];
                #pragma unroll
                for (int rr = 0; rr < 4; ++rr) pk[rr] = f2bf(acc[i][j][rr] + bcol[j]);
                *(uint2*)&Vt[((size_t)g * DD + dim) * LM + key] = *(uint2*)pk;
            }
        }
    }
}

// ---------------------------------------------------------------- GEMM + residual(bf16) + LayerNorm fused
// 32 rows x 256 cols, 4 waves = 4 col slabs, grid NR/32. Residual in bf16 (Hb);
// in-place Hb update is safe (each element read+written by the same thread).
// PERM: final layer — write f32 to seq-first d_out, skip Hb.
template <bool PERM>
__global__ __launch_bounds__(256) void gemm_ln_kernel(
    const unsigned short* __restrict__ A, const unsigned short* __restrict__ Wt,
    const float* __restrict__ bias, const unsigned short* __restrict__ residb,
    const float* __restrict__ gam, const float* __restrict__ bet,
    float* __restrict__ outF, unsigned short* __restrict__ outHb, int K)
{
    __shared__ __align__(16) unsigned short As[32 * 32];
    __shared__ __align__(16) unsigned short Bs[256 * 32];
    __shared__ float red[2][4][32];
    const int t = threadIdx.x;
    const int wave = t >> 6, lane = t & 63;
    const int quad = lane >> 4, r16 = lane & 15;
    const int wc = wave * 64;
    const int m0 = blockIdx.x * 32;
    const int sr = lane >> 2, sq = (lane & 3) * 8;

    f32x4 acc[2][4];
    #pragma unroll
    for (int i = 0; i < 2; ++i)
        #pragma unroll
        for (int j = 0; j < 4; ++j)
            acc[i][j] = (f32x4){0.f, 0.f, 0.f, 0.f};

    for (int k0 = 0; k0 < K; k0 += 32) {
        __syncthreads();
        if (wave < 2)
            gl_lds16(&A[(size_t)(m0 + wave * 16 + sr) * K + k0 + sq], As + wave * 512);
        #pragma unroll
        for (int c = 0; c < 4; ++c)
            gl_lds16(&Wt[(size_t)(wc + c * 16 + sr) * K + k0 + sq],
                     Bs + wave * 2048 + c * 512);
        __syncthreads();
        bf16x8 af[2], bfr[4];
        #pragma unroll
        for (int i = 0; i < 2; ++i)
            af[i] = *(const bf16x8*)&As[(i * 16 + r16) * 32 + quad * 8];
        #pragma unroll
        for (int j = 0; j < 4; ++j)
            bfr[j] = *(const bf16x8*)&Bs[(wc + j * 16 + r16) * 32 + quad * 8];
        #pragma unroll
        for (int i = 0; i < 2; ++i)
            #pragma unroll
            for (int j = 0; j < 4; ++j)
                acc[i][j] = __builtin_amdgcn_mfma_f32_16x16x32_bf16(
                    af[i], bfr[j], acc[i][j], 0, 0, 0);
    }

    float bcol[4];
    #pragma unroll
    for (int j = 0; j < 4; ++j) bcol[j] = bias[wc + j * 16 + r16];

    #pragma unroll
    for (int i = 0; i < 2; ++i) {
        const int row = i * 16 + quad * 4;
        #pragma unroll
        for (int rr = 0; rr < 4; ++rr) {
            const size_t rb = (size_t)(m0 + row + rr) * DD;
            float s1 = 0.f, s2 = 0.f;
            #pragma unroll
            for (int j = 0; j < 4; ++j) {
                float v = acc[i][j][rr] + bcol[j] + bf2f(residb[rb + wc + j * 16 + r16]);
                acc[i][j][rr] = v;
                s1 += v;
                s2 += v * v;
            }
            #pragma unroll
            for (int off = 1; off < 16; off <<= 1) {
                s1 += __shfl_xor(s1, off, 64);
                s2 += __shfl_xor(s2, off, 64);
            }
            if (r16 == 0) {
                red[0][wave][row + rr] = s1;
                red[1][wave][row + rr] = s2;
            }
        }
    }
    __syncthreads();
    #pragma unroll
    for (int i = 0; i < 2; ++i) {
        const int row = i * 16 + quad * 4;
        #pragma unroll
        for (int rr = 0; rr < 4; ++rr) {
            const int gr = m0 + row + rr;
            float s1 = red[0][0][row + rr] + red[0][1][row + rr]
                     + red[0][2][row + rr] + red[0][3][row + rr];
            float s2 = red[1][0][row + rr] + red[1][1][row + rr]
                     + red[1][2][row + rr] + red[1][3][row + rr];
            float mean = s1 * (1.f / 256.f);
            float var  = s2 * (1.f / 256.f) - mean * mean;
            float rs = rsqrtf(var + 1e-5f);
            const size_t hb = (size_t)gr * DD;
            size_t fb = 0;
            if (PERM) {
                int gg = gr / LM, pos = gr - gg * LM;
                fb = ((size_t)pos * NG + gg) * DD;
            }
            #pragma unroll
            for (int j = 0; j < 4; ++j) {
                const int col = wc + j * 16 + r16;
                float ov = (acc[i][j][rr] - mean) * rs * gam[col] + bet[col];
                if (PERM) outF[fb + col] = ov;
                else      outHb[hb + col] = f2bf(ov);
            }
        }
    }
}

// ---------------------------------------------------------------- pack to graph-major padded [g][pos][D] (bf16 only)
__global__ __launch_bounds__(256) void pack_kernel(
    const float* __restrict__ z, const int* __restrict__ batches,
    unsigned short* __restrict__ Hb)
{
    int node = blockIdx.x * 4 + (threadIdx.x >> 6);
    int lane = threadIdx.x & 63;
    int lo = 0, hi = NG;
    while (lo < hi) {
        int mid = (lo + hi + 1) >> 1;
        if (batches[mid] <= node) lo = mid; else hi = mid - 1;
    }
    int pos = node - batches[lo];
    size_t base = ((size_t)lo * LM + pos) * DD + lane * 4;
    float4 zv = *(const float4*)(z + (size_t)node * DD + lane * 4);
    ushort4 hb;
    hb.x = f2bf(zv.x); hb.y = f2bf(zv.y); hb.z = f2bf(zv.z); hb.w = f2bf(zv.w);
    *(ushort4*)(Hb + base) = hb;
}

// ---------------------------------------------------------------- MFMA flash attention (no barriers)
__global__ __launch_bounds__(256) void attn_mfma_kernel(
    const unsigned short* __restrict__ qk, const unsigned short* __restrict__ vt,
    const int* __restrict__ batches, unsigned short* __restrict__ o)
{
    __shared__ __align__(16) unsigned short Pa[4][32 * 40];
    const int bx = blockIdx.x;
    const int g = bx & 63;
    const int r = bx >> 6;            // 0..19
    const int q0 = (r >> 1) * 32;
    const int tid = threadIdx.x;
    const int wave = tid >> 6;
    const int h = (r & 1) * 4 + wave;
    const int lane = tid & 63;
    const int quad = lane >> 4, r16 = lane & 15;
    const int len = batches[g + 1] - batches[g];
    const size_t gq = (size_t)g * LM;
    unsigned short* pa = Pa[wave];

    bf16x8 qf[2];
    #pragma unroll
    for (int i = 0; i < 2; ++i)
        qf[i] = *(const bf16x8*)(qk + (gq + q0 + i * 16 + r16) * QKW + h * 32 + quad * 8);
    bf16x8 onesf;
    #pragma unroll
    for (int j = 0; j < 8; ++j) onesf[j] = (short)0x3F80;   // bf16 1.0

    f32x4 oacc[2][2], lacc[2];
    #pragma unroll
    for (int i = 0; i < 2; ++i) {
        lacc[i] = (f32x4){0.f, 0.f, 0.f, 0.f};
        #pragma unroll
        for (int nt = 0; nt < 2; ++nt)
            oacc[i][nt] = (f32x4){0.f, 0.f, 0.f, 0.f};
    }

    for (int t0 = 0; t0 < len; t0 += 32) {
        bf16x8 kf[2], vf[2];
        #pragma unroll
        for (int mt = 0; mt < 2; ++mt) {
            int kr = t0 + mt * 16 + r16; if (kr > LM - 1) kr = LM - 1;
            kf[mt] = *(const bf16x8*)(qk + (gq + kr) * QKW + 256 + h * 32 + quad * 8);
        }
        #pragma unroll
        for (int nt = 0; nt < 2; ++nt)
            vf[nt] = *(const bf16x8*)(vt + ((size_t)g * DD + h * 32 + nt * 16 + r16) * LM
                                      + t0 + quad * 8);
        f32x4 st[2][2];
        #pragma unroll
        for (int mt = 0; mt < 2; ++mt)
            #pragma unroll
            for (int i = 0; i < 2; ++i)
                st[mt][i] = (f32x4){0.f, 0.f, 0.f, 0.f};
        #pragma unroll
        for (int mt = 0; mt < 2; ++mt)
            #pragma unroll
            for (int i = 0; i < 2; ++i)
                st[mt][i] = __builtin_amdgcn_mfma_f32_16x16x32_bf16(
                    kf[mt], qf[i], st[mt][i], 0, 0, 0);
        #pragma unroll
        for (int i = 0; i < 2; ++i) {
            #pragma unroll
            for (int mt = 0; mt < 2; ++mt) {
                float pr[4];
                #pragma unroll
                for (int rr = 0; rr < 4; ++rr) {
                    int key = t0 + mt * 16 + quad * 4 + rr;
                    pr[rr] = (key < len) ? __expf(st[mt][i][rr]) : 0.f;
                }
                uint2 w;
                w.x = ((unsigned)f2bf(pr[1]) << 16) | f2bf(pr[0]);
                w.y = ((unsigned)f2bf(pr[3]) << 16) | f2bf(pr[2]);
                *(uint2*)&pa[(i * 16 + r16) * 40 + mt * 16 + quad * 4] = w;
            }
        }
        __asm__ volatile("s_waitcnt lgkmcnt(0)" ::: "memory");
        bf16x8 pf[2];
        #pragma unroll
        for (int i = 0; i < 2; ++i)
            pf[i] = *(const bf16x8*)&pa[(i * 16 + r16) * 40 + quad * 8];
        #pragma unroll
        for (int i = 0; i < 2; ++i) {
            #pragma unroll
            for (int nt = 0; nt < 2; ++nt)
                oacc[i][nt] = __builtin_amdgcn_mfma_f32_16x16x32_bf16(
                    pf[i], vf[nt], oacc[i][nt], 0, 0, 0);
            lacc[i] = __builtin_amdgcn_mfma_f32_16x16x32_bf16(
                pf[i], onesf, lacc[i], 0, 0, 0);
        }
    }
    #pragma unroll
    for (int i = 0; i < 2; ++i) {
        #pragma unroll
        for (int rr = 0; rr < 4; ++rr) {
            float inv = 1.f / lacc[i][rr];
            size_t base = (gq + q0 + i * 16 + quad * 4 + rr) * DD + h * 32;
            #pragma unroll
            for (int nt = 0; nt < 2; ++nt)
                o[base + nt * 16 + r16] = f2bf(oacc[i][nt][rr] * inv);
        }
    }
}

// ---------------------------------------------------------------- launcher
extern "C" void kernel_launch(void* const* d_in, const int* in_sizes, int n_in,
                              void* d_out, int out_size, void* d_ws, size_t ws_size,
                              hipStream_t stream) {
    const float* x       = (const float*)d_in[0];
    const int*   ei      = (const int*)d_in[1];
    const int*   batches = (const int*)d_in[2];
    const float* sW0  = (const float*)d_in[4];
    const float* sWn0 = (const float*)d_in[5];
    const float* sb0  = (const float*)d_in[6];
    const float* sW1  = (const float*)d_in[7];
    const float* sWn1 = (const float*)d_in[8];
    const float* sb1  = (const float*)d_in[9];
    const float* sW2  = (const float*)d_in[10];
    const float* sWn2 = (const float*)d_in[11];
    const float* sb2  = (const float*)d_in[12];
    const float* Wq   = (const float*)d_in[13];
    const float* Wk   = (const float*)d_in[14];
    const float* Wv   = (const float*)d_in[15];
    const float* bq   = (const float*)d_in[16];
    const float* bk   = (const float*)d_in[17];
    const float* bv   = (const float*)d_in[18];
    const float* Wo   = (const float*)d_in[19];
    const float* bo   = (const float*)d_in[20];
    const float* ln1g = (const float*)d_in[21];
    const float* ln1b = (const float*)d_in[22];
    const float* ln2g = (const float*)d_in[23];
    const float* ln2b = (const float*)d_in[24];
    const float* W1   = (const float*)d_in[25];
    const float* b1   = (const float*)d_in[26];
    const float* W2   = (const float*)d_in[27];
    const float* b2   = (const float*)d_in[28];

    char* p = (char*)d_ws;
    auto alloc = [&](size_t bytes) {
        char* r = p;
        p += (bytes + 255) & ~(size_t)255;
        return r;
    };
    int*   counts  = (int*)alloc((size_t)NN * 4);
    int*   offsets = (int*)alloc((size_t)(NN + 1) * 4);
    int*   cursor  = (int*)alloc((size_t)NN * 4);
    int*   csr     = (int*)alloc((size_t)NE * 4);
    float* agg0    = (float*)alloc((size_t)NN * CIN * 4);
    unsigned short* z0b = (unsigned short*)alloc((size_t)NN * DD * 2);
    unsigned short* a1b = (unsigned short*)alloc((size_t)NN * DD * 2);
    unsigned short* z1b = (unsigned short*)alloc((size_t)NN * DD * 2);
    unsigned short* a2b = (unsigned short*)alloc((size_t)NN * DD * 2);
    float* z2f     = (float*)alloc((size_t)NN * DD * 4);   // dead after pack -> Vt aliases it
    unsigned short* Vt = (unsigned short*)z2f;             // [64][256][320] bf16 = 10.5 MB
    unsigned short* Hb = (unsigned short*)alloc((size_t)NR * DD * 2);
    unsigned short* Ob = (unsigned short*)alloc((size_t)NR * DD * 2);
    float* R       = (float*)alloc((size_t)NR * DFF * 2);  // QKb / F1b alias region (40 MB)
    unsigned short* QKb = (unsigned short*)R;              // [NR][512] bf16 = 21 MB
    unsigned short* F1b = (unsigned short*)R;              // [NR][1024] bf16 = 40 MB
    unsigned short* Wqkvt = (unsigned short*)alloc((size_t)NLY * QS * DD * 2);
    unsigned short* Wot   = (unsigned short*)alloc((size_t)NLY * DD * DD * 2);
    unsigned short* W1t   = (unsigned short*)alloc((size_t)NLY * DFF * DD * 2);
    unsigned short* W2t   = (unsigned short*)alloc((size_t)NLY * DD * DFF * 2);
    unsigned short* sW1t  = (unsigned short*)alloc((size_t)DD * DD * 2);
    unsigned short* sWn1t = (unsigned short*)alloc((size_t)DD * DD * 2);
    unsigned short* sW2t  = (unsigned short*)alloc((size_t)DD * DD * 2);
    unsigned short* sWn2t = (unsigned short*)alloc((size_t)DD * DD * 2);
    float* bqkvp   = (float*)alloc((size_t)NLY * QS * 4);

    // ---- fused weight prep (1 dispatch) + zero (1 dispatch) ----
    prep_all_kernel<<<844, 256, 0, stream>>>(
        Wq, Wk, Wv, Wo, W1, W2, sW1, sWn1, sW2, sWn2, bq, bk, bv,
        Wqkvt, Wot, W1t, W2t, sW1t, sWn1t, sW2t, sWn2t, bqkvp);
    zero_ws_kernel<<<(NR * DD / 8 + 255) / 256, 256, 0, stream>>>(
        (uint4*)Hb, NR * DD / 8, counts);

    // ---- CSR build ----
    count_edges_kernel<<<NE / 256, 256, 0, stream>>>(ei + NE, counts);
    scan_kernel<<<1, 256, 0, stream>>>(counts, offsets, cursor);
    fill_csr_kernel<<<NE / 256, 256, 0, stream>>>(ei, ei + NE, cursor, csr);

    // ---- SAGE ----
    agg_mean16_kernel<<<NN / 16, 256, 0, stream>>>(x, offsets, csr, agg0);
    gemm_f32b_kernel<1, true><<<dim3(DD / 64, NN / 64), 256, 0, stream>>>(
        x, sW0, agg0, sWn0, sb0, z0b, NN, DD, CIN);
    agg_mean_b_kernel<<<NN / 4, 256, 0, stream>>>(z0b, offsets, csr, a1b);
    mfma_gemm_kernel<1, true, false, true><<<dim3(DD / 128, NN / 128), 256, 0, stream>>>(
        z0b, sW1t, a1b, sWn1t, sb1, nullptr, z1b, NN, DD, DD);
    agg_mean_b_kernel<<<NN / 4, 256, 0, stream>>>(z1b, offsets, csr, a2b);
    mfma_gemm_kernel<0, true, true, false><<<dim3(DD / 128, NN / 128), 256, 0, stream>>>(
        z1b, sW2t, a2b, sWn2t, sb2, z2f, nullptr, NN, DD, DD);

    // ---- pack (graph-major, bf16) ----
    pack_kernel<<<NN / 4, 256, 0, stream>>>(z2f, batches, Hb);

    // ---- transformer ----
    for (int l = 0; l < NLY; ++l) {
        gemm_qkv_kernel<<<dim3(QS / 128, NR / 128), 256, 0, stream>>>(
            Hb, Wqkvt + (size_t)l * QS * DD, bqkvp + (size_t)l * QS, QKb, Vt, DD);
        attn_mfma_kernel<<<NG * 20, 256, 0, stream>>>(QKb, Vt, batches, Ob);
        gemm_ln_kernel<false><<<NR / 32, 256, 0, stream>>>(
            Ob, Wot + (size_t)l * DD * DD, bo + (size_t)l * DD, Hb,
            ln1g + (size_t)l * DD, ln1b + (size_t)l * DD, nullptr, Hb, DD);
        mfma_gemm_kernel<1, false, false, true><<<dim3(DFF / 128, NR / 128), 256, 0, stream>>>(
            Hb, W1t + (size_t)l * DFF * DD, nullptr, nullptr,
            b1 + (size_t)l * DFF, nullptr, F1b, NR, DFF, DD);
        if (l == NLY - 1)
            gemm_ln_kernel<true><<<NR / 32, 256, 0, stream>>>(
                F1b, W2t + (size_t)l * DD * DFF, b2 + (size_t)l * DD, Hb,
                ln2g + (size_t)l * DD, ln2b + (size_t)l * DD, (float*)d_out, Hb, DFF);
        else
            gemm_ln_kernel<false><<<NR / 32, 256, 0, stream>>>(
                F1b, W2t + (size_t)l * DD * DFF, b2 + (size_t)l * DD, Hb,
                ln2g + (size_t)l * DD, ln2b + (size_t)l * DD, nullptr, Hb, DFF);
    }
}